// Round 2
// baseline (12930.313 us; speedup 1.0000x reference)
//
#include <hip/hip_runtime.h>

#define B_ 64
#define T_ 383
#define S_ 384
#define ENC_ 768
#define TAGD_ 128
#define D_ 896
#define HG_ 400
#define HE_ 256
#define MSTEP_ 20
#define RTOT_ (B_*S_)                    // 24576
#define HEAD_SZ_ ((size_t)RTOT_*TAGD_)   // 3145728

typedef short short8 __attribute__((ext_vector_type(8)));
typedef float f32x4 __attribute__((ext_vector_type(4)));

__device__ __forceinline__ float bf2f(unsigned short u){
  union { unsigned int i; float f; } v; v.i = ((unsigned int)u) << 16; return v.f;
}
__device__ __forceinline__ unsigned short f2bf(float f){
  union { float f; unsigned int i; } v; v.f = f;
  unsigned int r = (v.i + 0x7fffu + ((v.i >> 16) & 1u)) >> 16;
  return (unsigned short)r;
}
__device__ __forceinline__ float tanh_fast(float x){
  float xc = fminf(fmaxf(x, -15.f), 15.f);
  float e = __expf(2.f*xc);
  return (e - 1.f) * __builtin_amdgcn_rcpf(e + 1.f);
}

// ---------------------------------------------------------------------------
// Runtime MFMA C/D-layout discovery (probe MFMAs) — used by the GEMM kernels.
// ---------------------------------------------------------------------------
__device__ __forceinline__ void probe_maps(int lane, int* mlab, int* nlab){
  unsigned short lb = f2bf((float)(lane & 15));
  short8 av, bv;
  #pragma unroll
  for (int j = 0; j < 8; j++){ av[j] = (short)lb; bv[j] = (short)0x3F80; } // bf16(1.0)
  f32x4 z = {0.f,0.f,0.f,0.f};
  f32x4 d1 = __builtin_amdgcn_mfma_f32_16x16x32_bf16(av, bv, z, 0, 0, 0);
  f32x4 d2 = __builtin_amdgcn_mfma_f32_16x16x32_bf16(bv, av, z, 0, 0, 0);
  #pragma unroll
  for (int i = 0; i < 4; i++){
    mlab[i] = (int)(d1[i]*0.03125f + 0.5f);
    nlab[i] = (int)(d2[i]*0.03125f + 0.5f);
  }
}

// Generic float -> bf16 (n multiple of 4)
__global__ __launch_bounds__(256) void cvt4(const float* __restrict__ src,
                                            unsigned short* __restrict__ dst, int n4)
{
  int i = blockIdx.x*256 + threadIdx.x;
  if (i >= n4) return;
  float4 v = ((const float4*)src)[i];
  ((ushort4*)dst)[i] = make_ushort4(f2bf(v.x), f2bf(v.y), f2bf(v.z), f2bf(v.w));
}

// ---------------------------------------------------------------------------
// Pack Whh_f / Whh_b into single bf16 [dir][n:416][k:416], zero-padded.
// ---------------------------------------------------------------------------
__global__ __launch_bounds__(256) void pack_wrnn2(const float* __restrict__ Wf,
                                                  const float* __restrict__ Wb,
                                                  unsigned short* __restrict__ Wr)
{
  int idx = blockIdx.x*256 + threadIdx.x;
  if (idx >= 2*416*416) return;
  int dir = idx / (416*416);
  int rem = idx % (416*416);
  int n = rem / 416, k = rem % 416;
  unsigned short v = 0;
  if (n < HG_ && k < HG_) v = f2bf((dir ? Wb : Wf)[(size_t)n*HG_ + k]);
  Wr[idx] = v;
}

// ---------------------------------------------------------------------------
// Pack mask into per-t 64-bit bitmasks (bit b = mask[b][t-1]; t=0 -> all 1s).
// ---------------------------------------------------------------------------
__global__ __launch_bounds__(64) void maskpack(const int* __restrict__ mask,
                                               unsigned long long* __restrict__ mb)
{
  int t = blockIdx.x; int b = threadIdx.x;
  int m = (t > 0) ? mask[b*T_ + (t-1)] : 1;
  unsigned long long v = __ballot(m != 0);
  if (b == 0) mb[t] = v;
}

// ---------------------------------------------------------------------------
// preT[dir][t][n][b] = X[b,t].Wihcat[dir*400+n] + bih[n] + bhh[n], bf16.
// ---------------------------------------------------------------------------
__global__ __launch_bounds__(256) void gemm_pre(
    const float* __restrict__ inp, const float* __restrict__ tag,
    const float* __restrict__ sent, const unsigned short* __restrict__ W,
    const float* __restrict__ bihf, const float* __restrict__ bhhf,
    const float* __restrict__ bihb, const float* __restrict__ bhhb,
    unsigned short* __restrict__ preT)
{
  int wid = blockIdx.x*4 + (threadIdx.x >> 6);
  int lane = threadIdx.x & 63;
  int q = lane >> 4, l16 = lane & 15;
  int mt = wid / 25, ct = wid % 25;
  int r = mt*16 + l16;
  int s = r % S_, b = r / S_;
  int mlab[4], nlab[4];
  probe_maps(lane, mlab, nlab);
  int n0 = ct*32 + l16, n1 = n0 + 16;
  const unsigned short* w0 = W + (size_t)n0*D_;
  const unsigned short* w1 = W + (size_t)n1*D_;
  f32x4 acc0 = {0.f,0.f,0.f,0.f}, acc1 = {0.f,0.f,0.f,0.f};
  for (int k0 = 0; k0 < D_; k0 += 32){
    int k = k0 + q*8;   // 8-float group never straddles the 768 boundary
    const float* asrc = (s == 0) ? (sent + k)
        : ((k < ENC_) ? inp + (size_t)(b*T_ + (s-1))*ENC_ + k
                      : tag + (size_t)(b*T_ + (s-1))*TAGD_ + (k - ENC_));
    float4 v0 = *(const float4*)asrc;
    float4 v1 = *(const float4*)(asrc + 4);
    short8 a;
    a[0]=(short)f2bf(v0.x); a[1]=(short)f2bf(v0.y); a[2]=(short)f2bf(v0.z); a[3]=(short)f2bf(v0.w);
    a[4]=(short)f2bf(v1.x); a[5]=(short)f2bf(v1.y); a[6]=(short)f2bf(v1.z); a[7]=(short)f2bf(v1.w);
    acc0 = __builtin_amdgcn_mfma_f32_16x16x32_bf16(a, *(const short8*)(w0 + k), acc0, 0,0,0);
    acc1 = __builtin_amdgcn_mfma_f32_16x16x32_bf16(a, *(const short8*)(w1 + k), acc1, 0,0,0);
  }
  #pragma unroll
  for (int i = 0; i < 4; i++){
    int row = mt*16 + mlab[i];
    int c0 = ct*32 + nlab[i], c1 = c0 + 16;
    int bb = row / S_, ss = row % S_;
    float v0 = acc0[i] + ((c0 < HG_) ? (bihf[c0] + bhhf[c0]) : (bihb[c0-HG_] + bhhb[c0-HG_]));
    float v1 = acc1[i] + ((c1 < HG_) ? (bihf[c1] + bhhf[c1]) : (bihb[c1-HG_] + bhhb[c1-HG_]));
    int d0 = (c0 >= HG_) ? 1 : 0, nn0 = c0 - d0*HG_;
    int d1 = (c1 >= HG_) ? 1 : 0, nn1 = c1 - d1*HG_;
    preT[((size_t)(d0*S_ + ss)*400 + nn0)*64 + bb] = f2bf(v0);
    preT[((size_t)(d1*S_ + ss)*400 + nn1)*64 + bb] = f2bf(v1);
  }
}

// ---------------------------------------------------------------------------
// Batched masked RNN via MFMA, one block per direction (all 64 chains).
// 4 waves = n-groups over 26 n-tiles {7,7,6,6}. H in LDS as hi/lo bf16
// planes (f32-accurate recurrence); B (Whh) streamed from L2 once per step;
// h_prev carried in registers; in-place H update with 2 barriers/step.
// 1 wave/SIMD -> 512-VGPR budget (the round-1 kernel spilled at 256).
// ---------------------------------------------------------------------------
#define HSTRIDE_ 424   // shorts per H row (416 + 8 pad; 212 dwords -> 2-way banks)
template<int NTC>
__device__ void rnn_body(int nt0, int dir, int l16, int q,
    const unsigned short* __restrict__ preT,   // this dir's [t][n:400][b:64]
    const unsigned short* __restrict__ Wr,     // this dir's [n:416][k:416]
    const unsigned long long* __restrict__ mbits,
    unsigned short* __restrict__ gs,
    unsigned short (*Hh)[HSTRIDE_], unsigned short (*Hl)[HSTRIDE_])
{
  const unsigned short* wrow[NTC];
  #pragma unroll
  for (int j = 0; j < NTC; j++)
    wrow[j] = Wr + (size_t)((nt0 + j)*16 + l16)*416 + q*8;

  float hp[NTC][4][4];
  #pragma unroll
  for (int j = 0; j < NTC; j++)
    #pragma unroll
    for (int mt = 0; mt < 4; mt++)
      #pragma unroll
      for (int ri = 0; ri < 4; ri++) hp[j][mt][ri] = 0.f;

  for (int stp = 0; stp < S_; stp++){
    int t = dir ? (S_ - 1 - stp) : stp;
    unsigned long long mb = mbits[t];
    const unsigned short* pT = preT + (size_t)t*400*64;

    // pre loads for this step's epilogue: coalesced ushort4, hidden by kt loop
    ushort4 pu[NTC][4];
    #pragma unroll
    for (int j = 0; j < NTC; j++)
      #pragma unroll
      for (int mt = 0; mt < 4; mt++)
        pu[j][mt] = *(const ushort4*)(pT + (size_t)((nt0 + j)*16 + l16)*64 + mt*16 + q*4);

    f32x4 acc[NTC][4];
    #pragma unroll
    for (int j = 0; j < NTC; j++)
      #pragma unroll
      for (int mt = 0; mt < 4; mt++)
        acc[j][mt] = (f32x4){0.f,0.f,0.f,0.f};

    #pragma unroll
    for (int kt = 0; kt < 13; kt++){
      short8 bv[NTC], ah[4], al[4];
      #pragma unroll
      for (int j = 0; j < NTC; j++) bv[j] = *(const short8*)(wrow[j] + kt*32);
      #pragma unroll
      for (int mt = 0; mt < 4; mt++){
        ah[mt] = *(const short8*)&Hh[mt*16 + l16][kt*32 + q*8];
        al[mt] = *(const short8*)&Hl[mt*16 + l16][kt*32 + q*8];
      }
      #pragma unroll
      for (int mt = 0; mt < 4; mt++)
        #pragma unroll
        for (int j = 0; j < NTC; j++){
          acc[j][mt] = __builtin_amdgcn_mfma_f32_16x16x32_bf16(ah[mt], bv[j], acc[j][mt], 0,0,0);
          acc[j][mt] = __builtin_amdgcn_mfma_f32_16x16x32_bf16(al[mt], bv[j], acc[j][mt], 0,0,0);
        }
    }

    __syncthreads();   // all waves done reading H this step

    #pragma unroll
    for (int j = 0; j < NTC; j++){
      int n = (nt0 + j)*16 + l16;
      bool live = (n < HG_);
      #pragma unroll
      for (int mt = 0; mt < 4; mt++){
        unsigned short pv[4] = {pu[j][mt].x, pu[j][mt].y, pu[j][mt].z, pu[j][mt].w};
        #pragma unroll
        for (int ri = 0; ri < 4; ri++){
          int b = mt*16 + q*4 + ri;
          float hn = tanh_fast(acc[j][mt][ri] + bf2f(pv[ri]));
          bool mv = (mb >> b) & 1ull;
          float hnew = mv ? hn : hp[j][mt][ri];
          hp[j][mt][ri] = hnew;
          if (live){
            unsigned short hi = f2bf(hnew);
            Hh[b][n] = hi;
            Hl[b][n] = f2bf(hnew - bf2f(hi));
            gs[(size_t)(b*S_ + t)*800 + dir*HG_ + n] = mv ? f2bf(hn) : (unsigned short)0;
          }
        }
      }
    }
    __syncthreads();   // H writes visible before next step's reads
  }
}

__global__ __launch_bounds__(256, 1) void rnn_mfma2(
    const unsigned short* __restrict__ preT, const unsigned short* __restrict__ Wr,
    const unsigned long long* __restrict__ mbits, unsigned short* __restrict__ gs)
{
  __shared__ __align__(16) unsigned short Hbuf[2][64][HSTRIDE_];
  int tid = threadIdx.x;
  int wave = tid >> 6, lane = tid & 63, q = lane >> 4, l16 = lane & 15;
  int dir = blockIdx.x;
  for (int i = tid; i < 2*64*(HSTRIDE_/2); i += 256) ((unsigned int*)Hbuf)[i] = 0u;
  __syncthreads();
  const unsigned short* Wd = Wr + (size_t)dir*416*416;
  const unsigned short* pD = preT + (size_t)dir*S_*400*64;
  if (wave < 2) rnn_body<7>(wave*7,          dir, l16, q, pD, Wd, mbits, gs, Hbuf[0], Hbuf[1]);
  else          rnn_body<6>(14 + (wave-2)*6, dir, l16, q, pD, Wd, mbits, gs, Hbuf[0], Hbuf[1]);
}

// ---------------------------------------------------------------------------
// proj[r][n] = gs[r] . Wg2e[n] + bg2e[n]   (K=800, N=256), fp32 out
// ---------------------------------------------------------------------------
__global__ __launch_bounds__(256) void gemm_proj(
    const unsigned short* __restrict__ gs, const unsigned short* __restrict__ Wg2e,
    const float* __restrict__ bg2e, float* __restrict__ proj)
{
  int wid = blockIdx.x*4 + (threadIdx.x >> 6);
  int lane = threadIdx.x & 63;
  int q = lane >> 4, l16 = lane & 15;
  int mt = wid >> 3, ct = wid & 7;
  int mlab[4], nlab[4];
  probe_maps(lane, mlab, nlab);
  const unsigned short* arow = gs + (size_t)(mt*16 + l16)*800;
  int n0 = ct*32 + l16, n1 = n0 + 16;
  const unsigned short* w0 = Wg2e + (size_t)n0*800;
  const unsigned short* w1 = Wg2e + (size_t)n1*800;
  f32x4 acc0 = {0.f,0.f,0.f,0.f}, acc1 = {0.f,0.f,0.f,0.f};
  for (int k0 = 0; k0 < 800; k0 += 32){
    int k = k0 + q*8;
    short8 a = *(const short8*)(arow + k);
    acc0 = __builtin_amdgcn_mfma_f32_16x16x32_bf16(a, *(const short8*)(w0 + k), acc0, 0,0,0);
    acc1 = __builtin_amdgcn_mfma_f32_16x16x32_bf16(a, *(const short8*)(w1 + k), acc1, 0,0,0);
  }
  #pragma unroll
  for (int i = 0; i < 4; i++){
    int row = mt*16 + mlab[i];
    int c0 = ct*32 + nlab[i], c1 = c0 + 16;
    proj[(size_t)row*HE_ + c0] = acc0[i] + bg2e[c0];
    proj[(size_t)row*HE_ + c1] = acc1[i] + bg2e[c1];
  }
}

// ---------------------------------------------------------------------------
// head_tag / dep_tag = elu(gs @ Wtag^T + b), N=256 (c<128 head, else dep).
// ---------------------------------------------------------------------------
__global__ __launch_bounds__(256) void gemm_tag(
    const unsigned short* __restrict__ gs, const unsigned short* __restrict__ Wtag,
    const float* __restrict__ bht, const float* __restrict__ bdt,
    float* __restrict__ outH)
{
  int wid = blockIdx.x*4 + (threadIdx.x >> 6);
  int lane = threadIdx.x & 63;
  int q = lane >> 4, l16 = lane & 15;
  int mt = wid >> 3, ct = wid & 7;
  int mlab[4], nlab[4];
  probe_maps(lane, mlab, nlab);
  const unsigned short* arow = gs + (size_t)(mt*16 + l16)*800;
  int n0 = ct*32 + l16, n1 = n0 + 16;
  const unsigned short* w0 = Wtag + (size_t)n0*800;
  const unsigned short* w1 = Wtag + (size_t)n1*800;
  f32x4 acc0 = {0.f,0.f,0.f,0.f}, acc1 = {0.f,0.f,0.f,0.f};
  for (int k0 = 0; k0 < 800; k0 += 32){
    int k = k0 + q*8;
    short8 a = *(const short8*)(arow + k);
    acc0 = __builtin_amdgcn_mfma_f32_16x16x32_bf16(a, *(const short8*)(w0 + k), acc0, 0,0,0);
    acc1 = __builtin_amdgcn_mfma_f32_16x16x32_bf16(a, *(const short8*)(w1 + k), acc1, 0,0,0);
  }
  #pragma unroll
  for (int i = 0; i < 4; i++){
    int row = mt*16 + mlab[i];
    int c0 = ct*32 + nlab[i], c1 = c0 + 16;
    float v0 = acc0[i] + ((c0 < TAGD_) ? bht[c0] : bdt[c0-TAGD_]);
    float v1 = acc1[i] + ((c1 < TAGD_) ? bht[c1] : bdt[c1-TAGD_]);
    v0 = (v0 > 0.f) ? v0 : expm1f(v0);
    v1 = (v1 > 0.f) ? v1 : expm1f(v1);
    if (c0 < TAGD_) outH[(size_t)row*TAGD_ + c0] = v0;
    else            outH[HEAD_SZ_ + (size_t)row*TAGD_ + (c0-TAGD_)] = v0;
    if (c1 < TAGD_) outH[(size_t)row*TAGD_ + c1] = v1;
    else            outH[HEAD_SZ_ + (size_t)row*TAGD_ + (c1-TAGD_)] = v1;
  }
}

// ---------------------------------------------------------------------------
// estep scan, register-resident WhhE (unchanged from round 1 — it worked).
// ---------------------------------------------------------------------------
#define EROWS_ 96
#define ESTR_ 264
__global__ __launch_bounds__(256, 1) void estep2(
    const float* __restrict__ proj, const unsigned short* __restrict__ WhhE,
    const float* __restrict__ bihE, const float* __restrict__ bhhE,
    const float* __restrict__ WihE, const float* __restrict__ Wcls,
    const float* __restrict__ bclsp, const float* __restrict__ bosp,
    float* __restrict__ Ap)
{
  __shared__ __align__(16) unsigned short H[2][EROWS_][ESTR_];
  __shared__ float lacc[4][EROWS_];
  __shared__ float xls[EROWS_];
  int tid = threadIdx.x;
  int wave = tid >> 6, lane = tid & 63, q = lane >> 4, l16 = lane & 15;
  size_t rowbase = (size_t)blockIdx.x * EROWS_;

  short8 bw[4][8];
  float bias_n[4], wcl_n[4], wih_n[4];
  #pragma unroll
  for (int nt = 0; nt < 4; nt++){
    int n = wave*64 + nt*16 + l16;
    #pragma unroll
    for (int kt = 0; kt < 8; kt++)
      bw[nt][kt] = *(const short8*)(WhhE + (size_t)n*HE_ + kt*32 + q*8);
    bias_n[nt] = bihE[n] + bhhE[n];
    wcl_n[nt]  = Wcls[n];
    wih_n[nt]  = WihE[n];
  }
  for (int i = tid; i < EROWS_*HE_; i += 256){
    int r = i >> 8, n = i & 255;
    H[0][r][n] = f2bf(proj[(rowbase + r)*HE_ + n]);
  }
  if (tid < EROWS_) xls[tid] = bosp[0];
  float bc = bclsp[0];
  __syncthreads();

  for (int stp = 0; stp < MSTEP_; stp++){
    int cur = stp & 1, nxt = cur ^ 1;
    float lp[6][4];
    #pragma unroll
    for (int mt = 0; mt < 6; mt++){
      short8 af[8];
      #pragma unroll
      for (int kt = 0; kt < 8; kt++)
        af[kt] = *(const short8*)&H[cur][mt*16 + l16][kt*32 + q*8];
      float xr[4];
      #pragma unroll
      for (int ri = 0; ri < 4; ri++) xr[ri] = xls[mt*16 + q*4 + ri];
      f32x4 acc[4];
      #pragma unroll
      for (int nt = 0; nt < 4; nt++) acc[nt] = (f32x4){0.f,0.f,0.f,0.f};
      #pragma unroll
      for (int kt = 0; kt < 8; kt++){
        #pragma unroll
        for (int nt = 0; nt < 4; nt++)
          acc[nt] = __builtin_amdgcn_mfma_f32_16x16x32_bf16(af[kt], bw[nt][kt], acc[nt], 0,0,0);
      }
      #pragma unroll
      for (int ri = 0; ri < 4; ri++) lp[mt][ri] = 0.f;
      #pragma unroll
      for (int nt = 0; nt < 4; nt++){
        int n = wave*64 + nt*16 + l16;
        #pragma unroll
        for (int ri = 0; ri < 4; ri++){
          float v = acc[nt][ri] + bias_n[nt] + xr[ri]*wih_n[nt];
          float h = tanh_fast(v);
          lp[mt][ri] += h * wcl_n[nt];
          H[nxt][mt*16 + q*4 + ri][n] = f2bf(h);
        }
      }
    }
    #pragma unroll
    for (int mt = 0; mt < 6; mt++){
      #pragma unroll
      for (int ri = 0; ri < 4; ri++){
        float v = lp[mt][ri];
        v += __shfl_xor(v, 1, 16);
        v += __shfl_xor(v, 2, 16);
        v += __shfl_xor(v, 4, 16);
        v += __shfl_xor(v, 8, 16);
        lp[mt][ri] = v;
      }
    }
    if (l16 == 0){
      #pragma unroll
      for (int mt = 0; mt < 6; mt++)
        #pragma unroll
        for (int ri = 0; ri < 4; ri++)
          lacc[wave][mt*16 + q*4 + ri] = lp[mt][ri];
    }
    __syncthreads();
    if (tid < EROWS_){
      float lg = lacc[0][tid] + lacc[1][tid] + lacc[2][tid] + lacc[3][tid] + bc;
      Ap[(rowbase + tid)*MSTEP_ + stp] = lg;
      xls[tid] = lg;
    }
    __syncthreads();
  }
}

// ---------------------------------------------------------------------------
// arc_logits band gather -> float32
// ---------------------------------------------------------------------------
__global__ __launch_bounds__(256) void band_kernel(const float* __restrict__ Ap,
                                                   float* __restrict__ arc)
{
  int idx = blockIdx.x*256 + threadIdx.x;
  int c = idx % S_;
  int rr = (idx / S_) % S_;
  int b = idx / (S_*S_);
  int start = rr - MSTEP_; if (start < 0) start = 0;
  bool valid = (c >= start) && (c < rr);
  float v = 0.f;
  if (valid) v = Ap[(size_t)(b*S_ + rr)*MSTEP_ + (c - start)];
  arc[idx] = v;
}

// ---------------------------------------------------------------------------
extern "C" void kernel_launch(void* const* d_in, const int* in_sizes, int n_in,
                              void* d_out, int out_size, void* d_ws, size_t ws_size,
                              hipStream_t stream)
{
  const float* inp  = (const float*)d_in[0];
  const float* tag  = (const float*)d_in[1];
  const int*   mask = (const int*)d_in[2];
  const float* sent = (const float*)d_in[3];
  const float* Wihf = (const float*)d_in[4];
  const float* Whhf = (const float*)d_in[5];
  const float* bihf = (const float*)d_in[6];
  const float* bhhf = (const float*)d_in[7];
  const float* Wihb = (const float*)d_in[8];
  const float* Whhb = (const float*)d_in[9];
  const float* bihb = (const float*)d_in[10];
  const float* bhhb = (const float*)d_in[11];
  const float* Wg2e = (const float*)d_in[12];
  const float* bg2e = (const float*)d_in[13];
  const float* WihE = (const float*)d_in[14];
  const float* WhhE = (const float*)d_in[15];
  const float* bihE = (const float*)d_in[16];
  const float* bhhE = (const float*)d_in[17];
  const float* Wcls = (const float*)d_in[18];
  const float* bcls = (const float*)d_in[19];
  const float* bos  = (const float*)d_in[20];
  const float* Wht  = (const float*)d_in[21];
  const float* bht  = (const float*)d_in[22];
  const float* Wdt  = (const float*)d_in[23];
  const float* bdt  = (const float*)d_in[24];
  (void)in_sizes; (void)n_in; (void)out_size; (void)ws_size;

  char* ws = (char*)d_ws;
  unsigned short* preT   = (unsigned short*)ws;                        // 39,321,600 B
  unsigned short* gs     = (unsigned short*)(ws + 39321600);           // 39,321,600 B
  unsigned short* Wrnn2  = (unsigned short*)(ws + 78643200);           //    692,224 B
  unsigned short* Wihcat = (unsigned short*)(ws + 79335424);           //  1,433,600 B
  unsigned short* Wg2e_b = (unsigned short*)(ws + 80769024);           //    409,600 B
  unsigned short* Wtag_b = (unsigned short*)(ws + 81178624);           //    409,600 B
  unsigned short* WhhE_b = (unsigned short*)(ws + 81588224);           //    131,072 B
  unsigned long long* maskb = (unsigned long long*)(ws + 81719296);    //      3,072 B (end ~81.72 MB)
  // preT is dead after rnn_mfma2; proj/Ap alias into it.
  float*          proj   = (float*)ws;                                 // 25,165,824 B (alias)
  float*          Ap     = (float*)(ws + 25165824);                    //  1,966,080 B (alias)

  float* outH   = (float*)d_out;                 // f32: reference output dtype
  float* outArc = outH + 2*HEAD_SZ_;

  hipLaunchKernelGGL(cvt4, dim3(350), dim3(256), 0, stream, Wihf, Wihcat,           400*896/4);
  hipLaunchKernelGGL(cvt4, dim3(350), dim3(256), 0, stream, Wihb, Wihcat + 400*896, 400*896/4);
  hipLaunchKernelGGL(cvt4, dim3(200), dim3(256), 0, stream, Wg2e, Wg2e_b,           256*800/4);
  hipLaunchKernelGGL(cvt4, dim3(100), dim3(256), 0, stream, Wht,  Wtag_b,           128*800/4);
  hipLaunchKernelGGL(cvt4, dim3(100), dim3(256), 0, stream, Wdt,  Wtag_b + 128*800, 128*800/4);
  hipLaunchKernelGGL(cvt4, dim3(64),  dim3(256), 0, stream, WhhE, WhhE_b,           256*256/4);
  hipLaunchKernelGGL(pack_wrnn2, dim3(1352), dim3(256), 0, stream, Whhf, Whhb, Wrnn2);
  hipLaunchKernelGGL(maskpack, dim3(S_), dim3(64), 0, stream, mask, maskb);
  hipLaunchKernelGGL(gemm_pre, dim3(9600), dim3(256), 0, stream,
                     inp, tag, sent, Wihcat, bihf, bhhf, bihb, bhhb, preT);
  hipLaunchKernelGGL(rnn_mfma2, dim3(2), dim3(256), 0, stream, preT, Wrnn2, maskb, gs);
  hipLaunchKernelGGL(gemm_proj, dim3(3072), dim3(256), 0, stream, gs, Wg2e_b, bg2e, proj);
  hipLaunchKernelGGL(gemm_tag,  dim3(3072), dim3(256), 0, stream, gs, Wtag_b, bht, bdt, outH);
  hipLaunchKernelGGL(estep2, dim3(256), dim3(256), 0, stream,
                     proj, WhhE_b, bihE, bhhE, WihE, Wcls, bcls, bos, Ap);
  hipLaunchKernelGGL(band_kernel, dim3(36864), dim3(256), 0, stream, Ap, outArc);
}

// Round 3
// 11172.594 us; speedup vs baseline: 1.1573x; 1.1573x over previous
//
#include <hip/hip_runtime.h>

#define B_ 64
#define T_ 383
#define S_ 384
#define ENC_ 768
#define TAGD_ 128
#define D_ 896
#define HG_ 400
#define HE_ 256
#define MSTEP_ 20
#define RTOT_ (B_*S_)                    // 24576
#define HEAD_SZ_ ((size_t)RTOT_*TAGD_)   // 3145728

typedef short short8 __attribute__((ext_vector_type(8)));
typedef float f32x4 __attribute__((ext_vector_type(4)));

__device__ __forceinline__ float bf2f(unsigned short u){
  union { unsigned int i; float f; } v; v.i = ((unsigned int)u) << 16; return v.f;
}
__device__ __forceinline__ unsigned short f2bf(float f){
  union { float f; unsigned int i; } v; v.f = f;
  unsigned int r = (v.i + 0x7fffu + ((v.i >> 16) & 1u)) >> 16;
  return (unsigned short)r;
}
__device__ __forceinline__ float tanh_fast(float x){
  float xc = fminf(fmaxf(x, -15.f), 15.f);
  float e = __expf(2.f*xc);
  return (e - 1.f) * __builtin_amdgcn_rcpf(e + 1.f);
}

// ---------------------------------------------------------------------------
// Runtime MFMA C/D-layout discovery (probe MFMAs) — used by the GEMM kernels.
// ---------------------------------------------------------------------------
__device__ __forceinline__ void probe_maps(int lane, int* mlab, int* nlab){
  unsigned short lb = f2bf((float)(lane & 15));
  short8 av, bv;
  #pragma unroll
  for (int j = 0; j < 8; j++){ av[j] = (short)lb; bv[j] = (short)0x3F80; } // bf16(1.0)
  f32x4 z = {0.f,0.f,0.f,0.f};
  f32x4 d1 = __builtin_amdgcn_mfma_f32_16x16x32_bf16(av, bv, z, 0, 0, 0);
  f32x4 d2 = __builtin_amdgcn_mfma_f32_16x16x32_bf16(bv, av, z, 0, 0, 0);
  #pragma unroll
  for (int i = 0; i < 4; i++){
    mlab[i] = (int)(d1[i]*0.03125f + 0.5f);
    nlab[i] = (int)(d2[i]*0.03125f + 0.5f);
  }
}

// Generic float -> bf16 (n multiple of 4)
__global__ __launch_bounds__(256) void cvt4(const float* __restrict__ src,
                                            unsigned short* __restrict__ dst, int n4)
{
  int i = blockIdx.x*256 + threadIdx.x;
  if (i >= n4) return;
  float4 v = ((const float4*)src)[i];
  ((ushort4*)dst)[i] = make_ushort4(f2bf(v.x), f2bf(v.y), f2bf(v.z), f2bf(v.w));
}

// ---------------------------------------------------------------------------
// Pack Whh into coalesced MFMA-B tile layout:
//   Wr[dir][tile:26][kt:13][r:16][kk:32], element = W[n=tile*16+r][k=kt*32+kk]
// (zero-padded outside 400x400). A wave's per-(tile,kt) fragment load is one
// contiguous 4KB segment (64 lanes x 16B).
// ---------------------------------------------------------------------------
__global__ __launch_bounds__(256) void pack_wrnn3(const float* __restrict__ Wf,
                                                  const float* __restrict__ Wb,
                                                  unsigned short* __restrict__ Wr)
{
  int idx = blockIdx.x*256 + threadIdx.x;     // 2*26*13*16*32 = 346112 total
  if (idx >= 2*26*13*16*32) return;
  int dir = idx / (26*13*16*32);
  int rem = idx % (26*13*16*32);
  int tile = rem / (13*16*32); rem %= (13*16*32);
  int kt = rem / (16*32);      rem %= (16*32);
  int r  = rem / 32;
  int kk = rem % 32;
  int n = tile*16 + r, k = kt*32 + kk;
  unsigned short v = 0;
  if (n < HG_ && k < HG_) v = f2bf((dir ? Wb : Wf)[(size_t)n*HG_ + k]);
  Wr[idx] = v;
}

// ---------------------------------------------------------------------------
// Pack mask into per-t 64-bit bitmasks (bit b = mask[b][t-1]; t=0 -> all 1s).
// ---------------------------------------------------------------------------
__global__ __launch_bounds__(64) void maskpack(const int* __restrict__ mask,
                                               unsigned long long* __restrict__ mb)
{
  int t = blockIdx.x; int b = threadIdx.x;
  int m = (t > 0) ? mask[b*T_ + (t-1)] : 1;
  unsigned long long v = __ballot(m != 0);
  if (b == 0) mb[t] = v;
}

// ---------------------------------------------------------------------------
// preT[dir][t][n][b] = X[b,t].Wihcat[dir*400+n] + bih[n] + bhh[n], bf16.
// ---------------------------------------------------------------------------
__global__ __launch_bounds__(256) void gemm_pre(
    const float* __restrict__ inp, const float* __restrict__ tag,
    const float* __restrict__ sent, const unsigned short* __restrict__ W,
    const float* __restrict__ bihf, const float* __restrict__ bhhf,
    const float* __restrict__ bihb, const float* __restrict__ bhhb,
    unsigned short* __restrict__ preT)
{
  int wid = blockIdx.x*4 + (threadIdx.x >> 6);
  int lane = threadIdx.x & 63;
  int q = lane >> 4, l16 = lane & 15;
  int mt = wid / 25, ct = wid % 25;
  int r = mt*16 + l16;
  int s = r % S_, b = r / S_;
  int mlab[4], nlab[4];
  probe_maps(lane, mlab, nlab);
  int n0 = ct*32 + l16, n1 = n0 + 16;
  const unsigned short* w0 = W + (size_t)n0*D_;
  const unsigned short* w1 = W + (size_t)n1*D_;
  f32x4 acc0 = {0.f,0.f,0.f,0.f}, acc1 = {0.f,0.f,0.f,0.f};
  for (int k0 = 0; k0 < D_; k0 += 32){
    int k = k0 + q*8;   // 8-float group never straddles the 768 boundary
    const float* asrc = (s == 0) ? (sent + k)
        : ((k < ENC_) ? inp + (size_t)(b*T_ + (s-1))*ENC_ + k
                      : tag + (size_t)(b*T_ + (s-1))*TAGD_ + (k - ENC_));
    float4 v0 = *(const float4*)asrc;
    float4 v1 = *(const float4*)(asrc + 4);
    short8 a;
    a[0]=(short)f2bf(v0.x); a[1]=(short)f2bf(v0.y); a[2]=(short)f2bf(v0.z); a[3]=(short)f2bf(v0.w);
    a[4]=(short)f2bf(v1.x); a[5]=(short)f2bf(v1.y); a[6]=(short)f2bf(v1.z); a[7]=(short)f2bf(v1.w);
    acc0 = __builtin_amdgcn_mfma_f32_16x16x32_bf16(a, *(const short8*)(w0 + k), acc0, 0,0,0);
    acc1 = __builtin_amdgcn_mfma_f32_16x16x32_bf16(a, *(const short8*)(w1 + k), acc1, 0,0,0);
  }
  #pragma unroll
  for (int i = 0; i < 4; i++){
    int row = mt*16 + mlab[i];
    int c0 = ct*32 + nlab[i], c1 = c0 + 16;
    int bb = row / S_, ss = row % S_;
    float v0 = acc0[i] + ((c0 < HG_) ? (bihf[c0] + bhhf[c0]) : (bihb[c0-HG_] + bhhb[c0-HG_]));
    float v1 = acc1[i] + ((c1 < HG_) ? (bihf[c1] + bhhf[c1]) : (bihb[c1-HG_] + bhhb[c1-HG_]));
    int d0 = (c0 >= HG_) ? 1 : 0, nn0 = c0 - d0*HG_;
    int d1 = (c1 >= HG_) ? 1 : 0, nn1 = c1 - d1*HG_;
    preT[((size_t)(d0*S_ + ss)*400 + nn0)*64 + bb] = f2bf(v0);
    preT[((size_t)(d1*S_ + ss)*400 + nn1)*64 + bb] = f2bf(v1);
  }
}

// ---------------------------------------------------------------------------
// Batched masked RNN via MFMA, one block (4 waves) per direction.
// H in LDS as hi/lo bf16 planes (f32-accurate recurrence), updated IN PLACE
// with 2 barriers/step; h_prev re-read from LDS in the (rare) masked path,
// with an all-ones-mask fast path. No persistent register H state ->
// peak live set ~200 VGPRs (round-2 version spilled at the 256 cap).
// B streamed from L2 once per step in the coalesced tile layout.
// ---------------------------------------------------------------------------
#define HSTRIDE_ 424   // shorts per H row (416 + 8 pad)
template<int NTC>
__device__ void rnn_body(int nt0, int dir, int l16, int q,
    const unsigned short* __restrict__ preT,   // this dir's [t][n:400][b:64]
    const unsigned short* __restrict__ Wr,     // this dir's [tile][kt][16][32]
    const unsigned long long* __restrict__ mbits,
    unsigned short* __restrict__ gs,
    unsigned short (*Hh)[HSTRIDE_], unsigned short (*Hl)[HSTRIDE_])
{
  // per-tile coalesced B base pointers: tile stride = 13*512 shorts
  const unsigned short* wrow[NTC];
  bool tl[NTC];
  int nbase[NTC];
  #pragma unroll
  for (int j = 0; j < NTC; j++){
    wrow[j]  = Wr + (size_t)(nt0 + j)*13*512 + l16*32 + q*8;
    tl[j]    = ((nt0 + j)*16) < HG_;     // uniform per tile (tile 25 fully dead)
    nbase[j] = (nt0 + j)*16 + l16;
  }

  for (int stp = 0; stp < S_; stp++){
    int t = dir ? (S_ - 1 - stp) : stp;
    unsigned long long mb = mbits[t];
    bool allm = (mb == 0xFFFFFFFFFFFFFFFFull);
    const unsigned short* pT = preT + (size_t)t*400*64;

    f32x4 acc[NTC][4];
    #pragma unroll
    for (int j = 0; j < NTC; j++)
      #pragma unroll
      for (int mt = 0; mt < 4; mt++)
        acc[j][mt] = (f32x4){0.f,0.f,0.f,0.f};

    #pragma unroll
    for (int kt = 0; kt < 13; kt++){
      short8 bv[NTC], ah[4], al[4];
      #pragma unroll
      for (int j = 0; j < NTC; j++) bv[j] = *(const short8*)(wrow[j] + kt*512);
      #pragma unroll
      for (int mt = 0; mt < 4; mt++){
        ah[mt] = *(const short8*)&Hh[mt*16 + l16][kt*32 + q*8];
        al[mt] = *(const short8*)&Hl[mt*16 + l16][kt*32 + q*8];
      }
      #pragma unroll
      for (int mt = 0; mt < 4; mt++)
        #pragma unroll
        for (int j = 0; j < NTC; j++){
          acc[j][mt] = __builtin_amdgcn_mfma_f32_16x16x32_bf16(ah[mt], bv[j], acc[j][mt], 0,0,0);
          acc[j][mt] = __builtin_amdgcn_mfma_f32_16x16x32_bf16(al[mt], bv[j], acc[j][mt], 0,0,0);
        }
    }

    // pre loads issued here; they land while the barrier drains
    ushort4 pu[NTC][4];
    #pragma unroll
    for (int j = 0; j < NTC; j++)
      #pragma unroll
      for (int mt = 0; mt < 4; mt++)
        pu[j][mt] = tl[j] ? *(const ushort4*)(pT + (size_t)nbase[j]*64 + mt*16 + q*4)
                          : make_ushort4(0,0,0,0);

    __syncthreads();   // all waves done reading H this step

    if (allm){
      #pragma unroll
      for (int j = 0; j < NTC; j++){
        if (tl[j]){
          int n = nbase[j];
          #pragma unroll
          for (int mt = 0; mt < 4; mt++){
            unsigned short pv[4] = {pu[j][mt].x, pu[j][mt].y, pu[j][mt].z, pu[j][mt].w};
            #pragma unroll
            for (int ri = 0; ri < 4; ri++){
              int b = mt*16 + q*4 + ri;
              float hn = tanh_fast(acc[j][mt][ri] + bf2f(pv[ri]));
              unsigned short hi = f2bf(hn);
              Hh[b][n] = hi;
              Hl[b][n] = f2bf(hn - bf2f(hi));
              gs[(size_t)(b*S_ + t)*800 + dir*HG_ + n] = hi;
            }
          }
        }
      }
    } else {
      #pragma unroll
      for (int j = 0; j < NTC; j++){
        if (tl[j]){
          int n = nbase[j];
          #pragma unroll
          for (int mt = 0; mt < 4; mt++){
            unsigned short pv[4] = {pu[j][mt].x, pu[j][mt].y, pu[j][mt].z, pu[j][mt].w};
            #pragma unroll
            for (int ri = 0; ri < 4; ri++){
              int b = mt*16 + q*4 + ri;
              float hn = tanh_fast(acc[j][mt][ri] + bf2f(pv[ri]));
              bool mv = (mb >> b) & 1ull;
              float hold = bf2f(Hh[b][n]) + bf2f(Hl[b][n]);  // h_{t-1}, pre-overwrite
              float hnew = mv ? hn : hold;
              unsigned short hi = f2bf(hnew);
              Hh[b][n] = hi;
              Hl[b][n] = f2bf(hnew - bf2f(hi));
              gs[(size_t)(b*S_ + t)*800 + dir*HG_ + n] = mv ? f2bf(hn) : (unsigned short)0;
            }
          }
        }
      }
    }
    __syncthreads();   // H writes visible before next step's reads
  }
}

__global__ __launch_bounds__(256, 1) void rnn_mfma3(
    const unsigned short* __restrict__ preT, const unsigned short* __restrict__ Wr,
    const unsigned long long* __restrict__ mbits, unsigned short* __restrict__ gs)
{
  __shared__ __align__(16) unsigned short Hbuf[2][64][HSTRIDE_];
  int tid = threadIdx.x;
  int wave = tid >> 6, lane = tid & 63, q = lane >> 4, l16 = lane & 15;
  int dir = blockIdx.x;
  for (int i = tid; i < 2*64*(HSTRIDE_/2); i += 256) ((unsigned int*)Hbuf)[i] = 0u;
  __syncthreads();
  const unsigned short* Wd = Wr + (size_t)dir*26*13*512;
  const unsigned short* pD = preT + (size_t)dir*S_*400*64;
  if (wave < 2) rnn_body<7>(wave*7,          dir, l16, q, pD, Wd, mbits, gs, Hbuf[0], Hbuf[1]);
  else          rnn_body<6>(14 + (wave-2)*6, dir, l16, q, pD, Wd, mbits, gs, Hbuf[0], Hbuf[1]);
}

// ---------------------------------------------------------------------------
// proj[r][n] = gs[r] . Wg2e[n] + bg2e[n]   (K=800, N=256), fp32 out
// ---------------------------------------------------------------------------
__global__ __launch_bounds__(256) void gemm_proj(
    const unsigned short* __restrict__ gs, const unsigned short* __restrict__ Wg2e,
    const float* __restrict__ bg2e, float* __restrict__ proj)
{
  int wid = blockIdx.x*4 + (threadIdx.x >> 6);
  int lane = threadIdx.x & 63;
  int q = lane >> 4, l16 = lane & 15;
  int mt = wid >> 3, ct = wid & 7;
  int mlab[4], nlab[4];
  probe_maps(lane, mlab, nlab);
  const unsigned short* arow = gs + (size_t)(mt*16 + l16)*800;
  int n0 = ct*32 + l16, n1 = n0 + 16;
  const unsigned short* w0 = Wg2e + (size_t)n0*800;
  const unsigned short* w1 = Wg2e + (size_t)n1*800;
  f32x4 acc0 = {0.f,0.f,0.f,0.f}, acc1 = {0.f,0.f,0.f,0.f};
  for (int k0 = 0; k0 < 800; k0 += 32){
    int k = k0 + q*8;
    short8 a = *(const short8*)(arow + k);
    acc0 = __builtin_amdgcn_mfma_f32_16x16x32_bf16(a, *(const short8*)(w0 + k), acc0, 0,0,0);
    acc1 = __builtin_amdgcn_mfma_f32_16x16x32_bf16(a, *(const short8*)(w1 + k), acc1, 0,0,0);
  }
  #pragma unroll
  for (int i = 0; i < 4; i++){
    int row = mt*16 + mlab[i];
    int c0 = ct*32 + nlab[i], c1 = c0 + 16;
    proj[(size_t)row*HE_ + c0] = acc0[i] + bg2e[c0];
    proj[(size_t)row*HE_ + c1] = acc1[i] + bg2e[c1];
  }
}

// ---------------------------------------------------------------------------
// head_tag / dep_tag = elu(gs @ Wtag^T + b), N=256 (c<128 head, else dep).
// ---------------------------------------------------------------------------
__global__ __launch_bounds__(256) void gemm_tag(
    const unsigned short* __restrict__ gs, const unsigned short* __restrict__ Wtag,
    const float* __restrict__ bht, const float* __restrict__ bdt,
    float* __restrict__ outH)
{
  int wid = blockIdx.x*4 + (threadIdx.x >> 6);
  int lane = threadIdx.x & 63;
  int q = lane >> 4, l16 = lane & 15;
  int mt = wid >> 3, ct = wid & 7;
  int mlab[4], nlab[4];
  probe_maps(lane, mlab, nlab);
  const unsigned short* arow = gs + (size_t)(mt*16 + l16)*800;
  int n0 = ct*32 + l16, n1 = n0 + 16;
  const unsigned short* w0 = Wtag + (size_t)n0*800;
  const unsigned short* w1 = Wtag + (size_t)n1*800;
  f32x4 acc0 = {0.f,0.f,0.f,0.f}, acc1 = {0.f,0.f,0.f,0.f};
  for (int k0 = 0; k0 < 800; k0 += 32){
    int k = k0 + q*8;
    short8 a = *(const short8*)(arow + k);
    acc0 = __builtin_amdgcn_mfma_f32_16x16x32_bf16(a, *(const short8*)(w0 + k), acc0, 0,0,0);
    acc1 = __builtin_amdgcn_mfma_f32_16x16x32_bf16(a, *(const short8*)(w1 + k), acc1, 0,0,0);
  }
  #pragma unroll
  for (int i = 0; i < 4; i++){
    int row = mt*16 + mlab[i];
    int c0 = ct*32 + nlab[i], c1 = c0 + 16;
    float v0 = acc0[i] + ((c0 < TAGD_) ? bht[c0] : bdt[c0-TAGD_]);
    float v1 = acc1[i] + ((c1 < TAGD_) ? bht[c1] : bdt[c1-TAGD_]);
    v0 = (v0 > 0.f) ? v0 : expm1f(v0);
    v1 = (v1 > 0.f) ? v1 : expm1f(v1);
    if (c0 < TAGD_) outH[(size_t)row*TAGD_ + c0] = v0;
    else            outH[HEAD_SZ_ + (size_t)row*TAGD_ + (c0-TAGD_)] = v0;
    if (c1 < TAGD_) outH[(size_t)row*TAGD_ + c1] = v1;
    else            outH[HEAD_SZ_ + (size_t)row*TAGD_ + (c1-TAGD_)] = v1;
  }
}

// ---------------------------------------------------------------------------
// estep scan, register-resident WhhE.
// ---------------------------------------------------------------------------
#define EROWS_ 96
#define ESTR_ 264
__global__ __launch_bounds__(256, 1) void estep2(
    const float* __restrict__ proj, const unsigned short* __restrict__ WhhE,
    const float* __restrict__ bihE, const float* __restrict__ bhhE,
    const float* __restrict__ WihE, const float* __restrict__ Wcls,
    const float* __restrict__ bclsp, const float* __restrict__ bosp,
    float* __restrict__ Ap)
{
  __shared__ __align__(16) unsigned short H[2][EROWS_][ESTR_];
  __shared__ float lacc[4][EROWS_];
  __shared__ float xls[EROWS_];
  int tid = threadIdx.x;
  int wave = tid >> 6, lane = tid & 63, q = lane >> 4, l16 = lane & 15;
  size_t rowbase = (size_t)blockIdx.x * EROWS_;

  short8 bw[4][8];
  float bias_n[4], wcl_n[4], wih_n[4];
  #pragma unroll
  for (int nt = 0; nt < 4; nt++){
    int n = wave*64 + nt*16 + l16;
    #pragma unroll
    for (int kt = 0; kt < 8; kt++)
      bw[nt][kt] = *(const short8*)(WhhE + (size_t)n*HE_ + kt*32 + q*8);
    bias_n[nt] = bihE[n] + bhhE[n];
    wcl_n[nt]  = Wcls[n];
    wih_n[nt]  = WihE[n];
  }
  for (int i = tid; i < EROWS_*HE_; i += 256){
    int r = i >> 8, n = i & 255;
    H[0][r][n] = f2bf(proj[(rowbase + r)*HE_ + n]);
  }
  if (tid < EROWS_) xls[tid] = bosp[0];
  float bc = bclsp[0];
  __syncthreads();

  for (int stp = 0; stp < MSTEP_; stp++){
    int cur = stp & 1, nxt = cur ^ 1;
    float lp[6][4];
    #pragma unroll
    for (int mt = 0; mt < 6; mt++){
      short8 af[8];
      #pragma unroll
      for (int kt = 0; kt < 8; kt++)
        af[kt] = *(const short8*)&H[cur][mt*16 + l16][kt*32 + q*8];
      float xr[4];
      #pragma unroll
      for (int ri = 0; ri < 4; ri++) xr[ri] = xls[mt*16 + q*4 + ri];
      f32x4 acc[4];
      #pragma unroll
      for (int nt = 0; nt < 4; nt++) acc[nt] = (f32x4){0.f,0.f,0.f,0.f};
      #pragma unroll
      for (int kt = 0; kt < 8; kt++){
        #pragma unroll
        for (int nt = 0; nt < 4; nt++)
          acc[nt] = __builtin_amdgcn_mfma_f32_16x16x32_bf16(af[kt], bw[nt][kt], acc[nt], 0,0,0);
      }
      #pragma unroll
      for (int ri = 0; ri < 4; ri++) lp[mt][ri] = 0.f;
      #pragma unroll
      for (int nt = 0; nt < 4; nt++){
        int n = wave*64 + nt*16 + l16;
        #pragma unroll
        for (int ri = 0; ri < 4; ri++){
          float v = acc[nt][ri] + bias_n[nt] + xr[ri]*wih_n[nt];
          float h = tanh_fast(v);
          lp[mt][ri] += h * wcl_n[nt];
          H[nxt][mt*16 + q*4 + ri][n] = f2bf(h);
        }
      }
    }
    #pragma unroll
    for (int mt = 0; mt < 6; mt++){
      #pragma unroll
      for (int ri = 0; ri < 4; ri++){
        float v = lp[mt][ri];
        v += __shfl_xor(v, 1, 16);
        v += __shfl_xor(v, 2, 16);
        v += __shfl_xor(v, 4, 16);
        v += __shfl_xor(v, 8, 16);
        lp[mt][ri] = v;
      }
    }
    if (l16 == 0){
      #pragma unroll
      for (int mt = 0; mt < 6; mt++)
        #pragma unroll
        for (int ri = 0; ri < 4; ri++)
          lacc[wave][mt*16 + q*4 + ri] = lp[mt][ri];
    }
    __syncthreads();
    if (tid < EROWS_){
      float lg = lacc[0][tid] + lacc[1][tid] + lacc[2][tid] + lacc[3][tid] + bc;
      Ap[(rowbase + tid)*MSTEP_ + stp] = lg;
      xls[tid] = lg;
    }
    __syncthreads();
  }
}

// ---------------------------------------------------------------------------
// arc_logits band gather -> float32
// ---------------------------------------------------------------------------
__global__ __launch_bounds__(256) void band_kernel(const float* __restrict__ Ap,
                                                   float* __restrict__ arc)
{
  int idx = blockIdx.x*256 + threadIdx.x;
  int c = idx % S_;
  int rr = (idx / S_) % S_;
  int b = idx / (S_*S_);
  int start = rr - MSTEP_; if (start < 0) start = 0;
  bool valid = (c >= start) && (c < rr);
  float v = 0.f;
  if (valid) v = Ap[(size_t)(b*S_ + rr)*MSTEP_ + (c - start)];
  arc[idx] = v;
}

// ---------------------------------------------------------------------------
extern "C" void kernel_launch(void* const* d_in, const int* in_sizes, int n_in,
                              void* d_out, int out_size, void* d_ws, size_t ws_size,
                              hipStream_t stream)
{
  const float* inp  = (const float*)d_in[0];
  const float* tag  = (const float*)d_in[1];
  const int*   mask = (const int*)d_in[2];
  const float* sent = (const float*)d_in[3];
  const float* Wihf = (const float*)d_in[4];
  const float* Whhf = (const float*)d_in[5];
  const float* bihf = (const float*)d_in[6];
  const float* bhhf = (const float*)d_in[7];
  const float* Wihb = (const float*)d_in[8];
  const float* Whhb = (const float*)d_in[9];
  const float* bihb = (const float*)d_in[10];
  const float* bhhb = (const float*)d_in[11];
  const float* Wg2e = (const float*)d_in[12];
  const float* bg2e = (const float*)d_in[13];
  const float* WihE = (const float*)d_in[14];
  const float* WhhE = (const float*)d_in[15];
  const float* bihE = (const float*)d_in[16];
  const float* bhhE = (const float*)d_in[17];
  const float* Wcls = (const float*)d_in[18];
  const float* bcls = (const float*)d_in[19];
  const float* bos  = (const float*)d_in[20];
  const float* Wht  = (const float*)d_in[21];
  const float* bht  = (const float*)d_in[22];
  const float* Wdt  = (const float*)d_in[23];
  const float* bdt  = (const float*)d_in[24];
  (void)in_sizes; (void)n_in; (void)out_size; (void)ws_size;

  char* ws = (char*)d_ws;
  unsigned short* preT   = (unsigned short*)ws;                        // 39,321,600 B
  unsigned short* gs     = (unsigned short*)(ws + 39321600);           // 39,321,600 B
  unsigned short* Wrnn3  = (unsigned short*)(ws + 78643200);           //    692,224 B
  unsigned short* Wihcat = (unsigned short*)(ws + 79335424);           //  1,433,600 B
  unsigned short* Wg2e_b = (unsigned short*)(ws + 80769024);           //    409,600 B
  unsigned short* Wtag_b = (unsigned short*)(ws + 81178624);           //    409,600 B
  unsigned short* WhhE_b = (unsigned short*)(ws + 81588224);           //    131,072 B
  unsigned long long* maskb = (unsigned long long*)(ws + 81719296);    //      3,072 B (end ~81.72 MB)
  // preT is dead after rnn_mfma3; proj/Ap alias into it.
  float*          proj   = (float*)ws;                                 // 25,165,824 B (alias)
  float*          Ap     = (float*)(ws + 25165824);                    //  1,966,080 B (alias)

  float* outH   = (float*)d_out;                 // f32: reference output dtype
  float* outArc = outH + 2*HEAD_SZ_;

  hipLaunchKernelGGL(cvt4, dim3(350), dim3(256), 0, stream, Wihf, Wihcat,           400*896/4);
  hipLaunchKernelGGL(cvt4, dim3(350), dim3(256), 0, stream, Wihb, Wihcat + 400*896, 400*896/4);
  hipLaunchKernelGGL(cvt4, dim3(200), dim3(256), 0, stream, Wg2e, Wg2e_b,           256*800/4);
  hipLaunchKernelGGL(cvt4, dim3(100), dim3(256), 0, stream, Wht,  Wtag_b,           128*800/4);
  hipLaunchKernelGGL(cvt4, dim3(100), dim3(256), 0, stream, Wdt,  Wtag_b + 128*800, 128*800/4);
  hipLaunchKernelGGL(cvt4, dim3(64),  dim3(256), 0, stream, WhhE, WhhE_b,           256*256/4);
  hipLaunchKernelGGL(pack_wrnn3, dim3(1352), dim3(256), 0, stream, Whhf, Whhb, Wrnn3);
  hipLaunchKernelGGL(maskpack, dim3(S_), dim3(64), 0, stream, mask, maskb);
  hipLaunchKernelGGL(gemm_pre, dim3(9600), dim3(256), 0, stream,
                     inp, tag, sent, Wihcat, bihf, bhhf, bihb, bhhb, preT);
  hipLaunchKernelGGL(rnn_mfma3, dim3(2), dim3(256), 0, stream, preT, Wrnn3, maskb, gs);
  hipLaunchKernelGGL(gemm_proj, dim3(3072), dim3(256), 0, stream, gs, Wg2e_b, bg2e, proj);
  hipLaunchKernelGGL(gemm_tag,  dim3(3072), dim3(256), 0, stream, gs, Wtag_b, bht, bdt, outH);
  hipLaunchKernelGGL(estep2, dim3(256), dim3(256), 0, stream,
                     proj, WhhE_b, bihE, bhhE, WihE, Wcls, bcls, bos, Ap);
  hipLaunchKernelGGL(band_kernel, dim3(36864), dim3(256), 0, stream, Ap, outArc);
}

// Round 4
// 7694.437 us; speedup vs baseline: 1.6805x; 1.4520x over previous
//
#include <hip/hip_runtime.h>

#define B_ 64
#define T_ 383
#define S_ 384
#define ENC_ 768
#define TAGD_ 128
#define D_ 896
#define HG_ 400
#define HE_ 256
#define MSTEP_ 20
#define RTOT_ (B_*S_)                    // 24576
#define HEAD_SZ_ ((size_t)RTOT_*TAGD_)   // 3145728

typedef short short8 __attribute__((ext_vector_type(8)));
typedef float f32x4 __attribute__((ext_vector_type(4)));

__device__ __forceinline__ float bf2f(unsigned short u){
  union { unsigned int i; float f; } v; v.i = ((unsigned int)u) << 16; return v.f;
}
__device__ __forceinline__ unsigned short f2bf(float f){
  union { float f; unsigned int i; } v; v.f = f;
  unsigned int r = (v.i + 0x7fffu + ((v.i >> 16) & 1u)) >> 16;
  return (unsigned short)r;
}
__device__ __forceinline__ float tanh_fast(float x){
  float xc = fminf(fmaxf(x, -15.f), 15.f);
  float e = __expf(2.f*xc);
  return (e - 1.f) * __builtin_amdgcn_rcpf(e + 1.f);
}

// ---------------------------------------------------------------------------
// Runtime MFMA C/D-layout discovery (probe MFMAs) — used by the GEMM kernels.
// ---------------------------------------------------------------------------
__device__ __forceinline__ void probe_maps(int lane, int* mlab, int* nlab){
  unsigned short lb = f2bf((float)(lane & 15));
  short8 av, bv;
  #pragma unroll
  for (int j = 0; j < 8; j++){ av[j] = (short)lb; bv[j] = (short)0x3F80; } // bf16(1.0)
  f32x4 z = {0.f,0.f,0.f,0.f};
  f32x4 d1 = __builtin_amdgcn_mfma_f32_16x16x32_bf16(av, bv, z, 0, 0, 0);
  f32x4 d2 = __builtin_amdgcn_mfma_f32_16x16x32_bf16(bv, av, z, 0, 0, 0);
  #pragma unroll
  for (int i = 0; i < 4; i++){
    mlab[i] = (int)(d1[i]*0.03125f + 0.5f);
    nlab[i] = (int)(d2[i]*0.03125f + 0.5f);
  }
}

// Generic float -> bf16 (n multiple of 4)
__global__ __launch_bounds__(256) void cvt4(const float* __restrict__ src,
                                            unsigned short* __restrict__ dst, int n4)
{
  int i = blockIdx.x*256 + threadIdx.x;
  if (i >= n4) return;
  float4 v = ((const float4*)src)[i];
  ((ushort4*)dst)[i] = make_ushort4(f2bf(v.x), f2bf(v.y), f2bf(v.z), f2bf(v.w));
}

// ---------------------------------------------------------------------------
// Pack Whh into coalesced MFMA-B tile layout:
//   Wr[dir][tile:26][kt:13][r:16][kk:32], element = W[n=tile*16+r][k=kt*32+kk]
// ---------------------------------------------------------------------------
__global__ __launch_bounds__(256) void pack_wrnn3(const float* __restrict__ Wf,
                                                  const float* __restrict__ Wb,
                                                  unsigned short* __restrict__ Wr)
{
  int idx = blockIdx.x*256 + threadIdx.x;     // 2*26*13*16*32 = 346112 total
  if (idx >= 2*26*13*16*32) return;
  int dir = idx / (26*13*16*32);
  int rem = idx % (26*13*16*32);
  int tile = rem / (13*16*32); rem %= (13*16*32);
  int kt = rem / (16*32);      rem %= (16*32);
  int r  = rem / 32;
  int kk = rem % 32;
  int n = tile*16 + r, k = kt*32 + kk;
  unsigned short v = 0;
  if (n < HG_ && k < HG_) v = f2bf((dir ? Wb : Wf)[(size_t)n*HG_ + k]);
  Wr[idx] = v;
}

// ---------------------------------------------------------------------------
// Pack mask into per-t 64-bit bitmasks (bit b = mask[b][t-1]; t=0 -> all 1s).
// ---------------------------------------------------------------------------
__global__ __launch_bounds__(64) void maskpack(const int* __restrict__ mask,
                                               unsigned long long* __restrict__ mb)
{
  int t = blockIdx.x; int b = threadIdx.x;
  int m = (t > 0) ? mask[b*T_ + (t-1)] : 1;
  unsigned long long v = __ballot(m != 0);
  if (b == 0) mb[t] = v;
}

// ---------------------------------------------------------------------------
// preT2: fragment-order pre layout, so the RNN reads one coalesced ushort4
// per lane per (ntile, mtile):
//   preT2[dir][t][nt:25][mt:4][lane:64][ri:4],
//   value = pre[b = mt*16 + (lane>>4)*4 + ri][n = nt*16 + (lane&15)]
// ---------------------------------------------------------------------------
__global__ __launch_bounds__(256) void gemm_pre(
    const float* __restrict__ inp, const float* __restrict__ tag,
    const float* __restrict__ sent, const unsigned short* __restrict__ W,
    const float* __restrict__ bihf, const float* __restrict__ bhhf,
    const float* __restrict__ bihb, const float* __restrict__ bhhb,
    unsigned short* __restrict__ preT2)
{
  int wid = blockIdx.x*4 + (threadIdx.x >> 6);
  int lane = threadIdx.x & 63;
  int q = lane >> 4, l16 = lane & 15;
  int mt = wid / 25, ct = wid % 25;
  int r = mt*16 + l16;
  int s = r % S_, b = r / S_;
  int mlab[4], nlab[4];
  probe_maps(lane, mlab, nlab);
  int n0 = ct*32 + l16, n1 = n0 + 16;
  const unsigned short* w0 = W + (size_t)n0*D_;
  const unsigned short* w1 = W + (size_t)n1*D_;
  f32x4 acc0 = {0.f,0.f,0.f,0.f}, acc1 = {0.f,0.f,0.f,0.f};
  for (int k0 = 0; k0 < D_; k0 += 32){
    int k = k0 + q*8;   // 8-float group never straddles the 768 boundary
    const float* asrc = (s == 0) ? (sent + k)
        : ((k < ENC_) ? inp + (size_t)(b*T_ + (s-1))*ENC_ + k
                      : tag + (size_t)(b*T_ + (s-1))*TAGD_ + (k - ENC_));
    float4 v0 = *(const float4*)asrc;
    float4 v1 = *(const float4*)(asrc + 4);
    short8 a;
    a[0]=(short)f2bf(v0.x); a[1]=(short)f2bf(v0.y); a[2]=(short)f2bf(v0.z); a[3]=(short)f2bf(v0.w);
    a[4]=(short)f2bf(v1.x); a[5]=(short)f2bf(v1.y); a[6]=(short)f2bf(v1.z); a[7]=(short)f2bf(v1.w);
    acc0 = __builtin_amdgcn_mfma_f32_16x16x32_bf16(a, *(const short8*)(w0 + k), acc0, 0,0,0);
    acc1 = __builtin_amdgcn_mfma_f32_16x16x32_bf16(a, *(const short8*)(w1 + k), acc1, 0,0,0);
  }
  #pragma unroll
  for (int i = 0; i < 4; i++){
    int row = mt*16 + mlab[i];
    int c0 = ct*32 + nlab[i], c1 = c0 + 16;
    int bb = row / S_, ss = row % S_;
    int mtb = bb >> 4, qb = (bb >> 2) & 3, rib = bb & 3;
    float v0 = acc0[i] + ((c0 < HG_) ? (bihf[c0] + bhhf[c0]) : (bihb[c0-HG_] + bhhb[c0-HG_]));
    float v1 = acc1[i] + ((c1 < HG_) ? (bihf[c1] + bhhf[c1]) : (bihb[c1-HG_] + bhhb[c1-HG_]));
    {
      int d = (c0 >= HG_) ? 1 : 0; int nn = c0 - d*HG_;
      int nt = nn >> 4, lc = nn & 15;
      preT2[((((size_t)(d*S_ + ss)*25 + nt)*4 + mtb)*64 + (qb*16 + lc))*4 + rib] = f2bf(v0);
    }
    {
      int d = (c1 >= HG_) ? 1 : 0; int nn = c1 - d*HG_;
      int nt = nn >> 4, lc = nn & 15;
      preT2[((((size_t)(d*S_ + ss)*25 + nt)*4 + mtb)*64 + (qb*16 + lc))*4 + rib] = f2bf(v1);
    }
  }
}

// ---------------------------------------------------------------------------
// Batched masked RNN via MFMA, one block (8 waves, 512 thr) per direction.
// n-split across waves (no B redundancy), full-m per wave -> acc[NTC][4].
// H in LDS as hi/lo bf16 planes (f32-accurate recurrence), updated in place.
// NO scattered global ops in the loop: pre read as coalesced ushort4
// fragments (preT2), gs written by a coalesced masked LDS->global copy.
// ---------------------------------------------------------------------------
#define HSTR4_ 424   // shorts per H row (416 + 8 pad)
template<int NTC>
__device__ void rnn_body4(int nt0, int dir, int lane, int tid,
    const unsigned short* __restrict__ pD,     // this dir: [t][25][4][64][4]
    const unsigned short* __restrict__ Wd,     // this dir: [26][13][16][32]
    const unsigned long long* __restrict__ mbits,
    unsigned short* __restrict__ gs,
    unsigned short (*Hh)[HSTR4_], unsigned short (*Hl)[HSTR4_])
{
  int q = lane >> 4, l16 = lane & 15;
  const unsigned short* wrow[NTC];
  bool tl[NTC];
  #pragma unroll
  for (int j = 0; j < NTC; j++){
    wrow[j] = Wd + (size_t)(nt0 + j)*13*512 + l16*32 + q*8;
    tl[j]   = (nt0 + j) < 25;
  }

  for (int stp = 0; stp < S_; stp++){
    int t = dir ? (S_ - 1 - stp) : stp;
    unsigned long long mb = mbits[t];
    bool allm = (mb == 0xFFFFFFFFFFFFFFFFull);
    const unsigned short* pT = pD + (size_t)t*25600;   // 25*4*64*4

    // coalesced pre fragments (latency hides under the kt loop)
    ushort4 pu[NTC][4];
    #pragma unroll
    for (int j = 0; j < NTC; j++)
      #pragma unroll
      for (int mt = 0; mt < 4; mt++)
        pu[j][mt] = tl[j] ? *(const ushort4*)(pT + ((((size_t)(nt0+j)*4 + mt)*64) + lane)*4)
                          : make_ushort4(0,0,0,0);

    f32x4 acc[NTC][4];
    #pragma unroll
    for (int j = 0; j < NTC; j++)
      #pragma unroll
      for (int mt = 0; mt < 4; mt++)
        acc[j][mt] = (f32x4){0.f,0.f,0.f,0.f};

    #pragma unroll
    for (int kt = 0; kt < 13; kt++){
      short8 bv[NTC], ah[4], al[4];
      #pragma unroll
      for (int j = 0; j < NTC; j++) bv[j] = *(const short8*)(wrow[j] + kt*512);
      #pragma unroll
      for (int mt = 0; mt < 4; mt++){
        ah[mt] = *(const short8*)&Hh[mt*16 + l16][kt*32 + q*8];
        al[mt] = *(const short8*)&Hl[mt*16 + l16][kt*32 + q*8];
      }
      #pragma unroll
      for (int mt = 0; mt < 4; mt++)
        #pragma unroll
        for (int j = 0; j < NTC; j++){
          acc[j][mt] = __builtin_amdgcn_mfma_f32_16x16x32_bf16(ah[mt], bv[j], acc[j][mt], 0,0,0);
          acc[j][mt] = __builtin_amdgcn_mfma_f32_16x16x32_bf16(al[mt], bv[j], acc[j][mt], 0,0,0);
        }
    }

    __syncthreads();   // all waves done reading H this step

    #pragma unroll
    for (int j = 0; j < NTC; j++){
      if (tl[j]){
        int n = (nt0 + j)*16 + l16;
        #pragma unroll
        for (int mt = 0; mt < 4; mt++){
          unsigned short pv[4] = {pu[j][mt].x, pu[j][mt].y, pu[j][mt].z, pu[j][mt].w};
          #pragma unroll
          for (int ri = 0; ri < 4; ri++){
            int b = mt*16 + q*4 + ri;
            float hn = tanh_fast(acc[j][mt][ri] + bf2f(pv[ri]));
            float hnew;
            if (allm) hnew = hn;
            else {
              bool mv = (mb >> b) & 1ull;
              float hold = bf2f(Hh[b][n]) + bf2f(Hl[b][n]);   // pre-overwrite
              hnew = mv ? hn : hold;
            }
            unsigned short hi = f2bf(hnew);
            Hh[b][n] = hi;
            Hl[b][n] = f2bf(hnew - bf2f(hi));
          }
        }
      }
    }
    __syncthreads();   // H writes visible to all

    // coalesced masked gs copy: gs[b][t][n] = mask ? Hh[b][n] : 0
    for (int c = tid; c < 3200; c += 512){       // 64 rows x 50 x (8 shorts)
      int b = c / 50, off = c - b*50;
      uint4 dv = *(const uint4*)&Hh[b][off*8];
      bool mv = (mb >> b) & 1ull;
      uint4 z = make_uint4(0,0,0,0);
      *(uint4*)(gs + (size_t)(b*S_ + t)*800 + dir*HG_ + off*8) = mv ? dv : z;
    }
    // no third barrier: copy only reads Hh; next write to Hh is after the
    // next step's post-kt barrier, which orders these ds_reads.
  }
}

__global__ __launch_bounds__(512, 1) void rnn_mfma4(
    const unsigned short* __restrict__ preT2, const unsigned short* __restrict__ Wr,
    const unsigned long long* __restrict__ mbits, unsigned short* __restrict__ gs)
{
  __shared__ __align__(16) unsigned short Hh[64][HSTR4_];
  __shared__ __align__(16) unsigned short Hl[64][HSTR4_];
  int tid = threadIdx.x;
  int wave = tid >> 6, lane = tid & 63;
  int dir = blockIdx.x;
  for (int i = tid; i < 64*HSTR4_/2; i += 512){
    ((unsigned int*)Hh)[i] = 0u;
    ((unsigned int*)Hl)[i] = 0u;
  }
  __syncthreads();
  const unsigned short* Wd = Wr + (size_t)dir*26*13*512;
  const unsigned short* pD = preT2 + (size_t)dir*S_*25600;
  if (wave < 2) rnn_body4<4>(wave*4,          dir, lane, tid, pD, Wd, mbits, gs, Hh, Hl);
  else          rnn_body4<3>(8 + (wave-2)*3,  dir, lane, tid, pD, Wd, mbits, gs, Hh, Hl);
}

// ---------------------------------------------------------------------------
// proj[r][n] = gs[r] . Wg2e[n] + bg2e[n]   (K=800, N=256), fp32 out
// ---------------------------------------------------------------------------
__global__ __launch_bounds__(256) void gemm_proj(
    const unsigned short* __restrict__ gs, const unsigned short* __restrict__ Wg2e,
    const float* __restrict__ bg2e, float* __restrict__ proj)
{
  int wid = blockIdx.x*4 + (threadIdx.x >> 6);
  int lane = threadIdx.x & 63;
  int q = lane >> 4, l16 = lane & 15;
  int mt = wid >> 3, ct = wid & 7;
  int mlab[4], nlab[4];
  probe_maps(lane, mlab, nlab);
  const unsigned short* arow = gs + (size_t)(mt*16 + l16)*800;
  int n0 = ct*32 + l16, n1 = n0 + 16;
  const unsigned short* w0 = Wg2e + (size_t)n0*800;
  const unsigned short* w1 = Wg2e + (size_t)n1*800;
  f32x4 acc0 = {0.f,0.f,0.f,0.f}, acc1 = {0.f,0.f,0.f,0.f};
  for (int k0 = 0; k0 < 800; k0 += 32){
    int k = k0 + q*8;
    short8 a = *(const short8*)(arow + k);
    acc0 = __builtin_amdgcn_mfma_f32_16x16x32_bf16(a, *(const short8*)(w0 + k), acc0, 0,0,0);
    acc1 = __builtin_amdgcn_mfma_f32_16x16x32_bf16(a, *(const short8*)(w1 + k), acc1, 0,0,0);
  }
  #pragma unroll
  for (int i = 0; i < 4; i++){
    int row = mt*16 + mlab[i];
    int c0 = ct*32 + nlab[i], c1 = c0 + 16;
    proj[(size_t)row*HE_ + c0] = acc0[i] + bg2e[c0];
    proj[(size_t)row*HE_ + c1] = acc1[i] + bg2e[c1];
  }
}

// ---------------------------------------------------------------------------
// head_tag / dep_tag = elu(gs @ Wtag^T + b), N=256 (c<128 head, else dep).
// ---------------------------------------------------------------------------
__global__ __launch_bounds__(256) void gemm_tag(
    const unsigned short* __restrict__ gs, const unsigned short* __restrict__ Wtag,
    const float* __restrict__ bht, const float* __restrict__ bdt,
    float* __restrict__ outH)
{
  int wid = blockIdx.x*4 + (threadIdx.x >> 6);
  int lane = threadIdx.x & 63;
  int q = lane >> 4, l16 = lane & 15;
  int mt = wid >> 3, ct = wid & 7;
  int mlab[4], nlab[4];
  probe_maps(lane, mlab, nlab);
  const unsigned short* arow = gs + (size_t)(mt*16 + l16)*800;
  int n0 = ct*32 + l16, n1 = n0 + 16;
  const unsigned short* w0 = Wtag + (size_t)n0*800;
  const unsigned short* w1 = Wtag + (size_t)n1*800;
  f32x4 acc0 = {0.f,0.f,0.f,0.f}, acc1 = {0.f,0.f,0.f,0.f};
  for (int k0 = 0; k0 < 800; k0 += 32){
    int k = k0 + q*8;
    short8 a = *(const short8*)(arow + k);
    acc0 = __builtin_amdgcn_mfma_f32_16x16x32_bf16(a, *(const short8*)(w0 + k), acc0, 0,0,0);
    acc1 = __builtin_amdgcn_mfma_f32_16x16x32_bf16(a, *(const short8*)(w1 + k), acc1, 0,0,0);
  }
  #pragma unroll
  for (int i = 0; i < 4; i++){
    int row = mt*16 + mlab[i];
    int c0 = ct*32 + nlab[i], c1 = c0 + 16;
    float v0 = acc0[i] + ((c0 < TAGD_) ? bht[c0] : bdt[c0-TAGD_]);
    float v1 = acc1[i] + ((c1 < TAGD_) ? bht[c1] : bdt[c1-TAGD_]);
    v0 = (v0 > 0.f) ? v0 : expm1f(v0);
    v1 = (v1 > 0.f) ? v1 : expm1f(v1);
    if (c0 < TAGD_) outH[(size_t)row*TAGD_ + c0] = v0;
    else            outH[HEAD_SZ_ + (size_t)row*TAGD_ + (c0-TAGD_)] = v0;
    if (c1 < TAGD_) outH[(size_t)row*TAGD_ + c1] = v1;
    else            outH[HEAD_SZ_ + (size_t)row*TAGD_ + (c1-TAGD_)] = v1;
  }
}

// ---------------------------------------------------------------------------
// estep scan, register-resident WhhE.
// ---------------------------------------------------------------------------
#define EROWS_ 96
#define ESTR_ 264
__global__ __launch_bounds__(256, 1) void estep2(
    const float* __restrict__ proj, const unsigned short* __restrict__ WhhE,
    const float* __restrict__ bihE, const float* __restrict__ bhhE,
    const float* __restrict__ WihE, const float* __restrict__ Wcls,
    const float* __restrict__ bclsp, const float* __restrict__ bosp,
    float* __restrict__ Ap)
{
  __shared__ __align__(16) unsigned short H[2][EROWS_][ESTR_];
  __shared__ float lacc[4][EROWS_];
  __shared__ float xls[EROWS_];
  int tid = threadIdx.x;
  int wave = tid >> 6, lane = tid & 63, q = lane >> 4, l16 = lane & 15;
  size_t rowbase = (size_t)blockIdx.x * EROWS_;

  short8 bw[4][8];
  float bias_n[4], wcl_n[4], wih_n[4];
  #pragma unroll
  for (int nt = 0; nt < 4; nt++){
    int n = wave*64 + nt*16 + l16;
    #pragma unroll
    for (int kt = 0; kt < 8; kt++)
      bw[nt][kt] = *(const short8*)(WhhE + (size_t)n*HE_ + kt*32 + q*8);
    bias_n[nt] = bihE[n] + bhhE[n];
    wcl_n[nt]  = Wcls[n];
    wih_n[nt]  = WihE[n];
  }
  for (int i = tid; i < EROWS_*HE_; i += 256){
    int r = i >> 8, n = i & 255;
    H[0][r][n] = f2bf(proj[(rowbase + r)*HE_ + n]);
  }
  if (tid < EROWS_) xls[tid] = bosp[0];
  float bc = bclsp[0];
  __syncthreads();

  for (int stp = 0; stp < MSTEP_; stp++){
    int cur = stp & 1, nxt = cur ^ 1;
    float lp[6][4];
    #pragma unroll
    for (int mt = 0; mt < 6; mt++){
      short8 af[8];
      #pragma unroll
      for (int kt = 0; kt < 8; kt++)
        af[kt] = *(const short8*)&H[cur][mt*16 + l16][kt*32 + q*8];
      float xr[4];
      #pragma unroll
      for (int ri = 0; ri < 4; ri++) xr[ri] = xls[mt*16 + q*4 + ri];
      f32x4 acc[4];
      #pragma unroll
      for (int nt = 0; nt < 4; nt++) acc[nt] = (f32x4){0.f,0.f,0.f,0.f};
      #pragma unroll
      for (int kt = 0; kt < 8; kt++){
        #pragma unroll
        for (int nt = 0; nt < 4; nt++)
          acc[nt] = __builtin_amdgcn_mfma_f32_16x16x32_bf16(af[kt], bw[nt][kt], acc[nt], 0,0,0);
      }
      #pragma unroll
      for (int ri = 0; ri < 4; ri++) lp[mt][ri] = 0.f;
      #pragma unroll
      for (int nt = 0; nt < 4; nt++){
        int n = wave*64 + nt*16 + l16;
        #pragma unroll
        for (int ri = 0; ri < 4; ri++){
          float v = acc[nt][ri] + bias_n[nt] + xr[ri]*wih_n[nt];
          float h = tanh_fast(v);
          lp[mt][ri] += h * wcl_n[nt];
          H[nxt][mt*16 + q*4 + ri][n] = f2bf(h);
        }
      }
    }
    #pragma unroll
    for (int mt = 0; mt < 6; mt++){
      #pragma unroll
      for (int ri = 0; ri < 4; ri++){
        float v = lp[mt][ri];
        v += __shfl_xor(v, 1, 16);
        v += __shfl_xor(v, 2, 16);
        v += __shfl_xor(v, 4, 16);
        v += __shfl_xor(v, 8, 16);
        lp[mt][ri] = v;
      }
    }
    if (l16 == 0){
      #pragma unroll
      for (int mt = 0; mt < 6; mt++)
        #pragma unroll
        for (int ri = 0; ri < 4; ri++)
          lacc[wave][mt*16 + q*4 + ri] = lp[mt][ri];
    }
    __syncthreads();
    if (tid < EROWS_){
      float lg = lacc[0][tid] + lacc[1][tid] + lacc[2][tid] + lacc[3][tid] + bc;
      Ap[(rowbase + tid)*MSTEP_ + stp] = lg;
      xls[tid] = lg;
    }
    __syncthreads();
  }
}

// ---------------------------------------------------------------------------
// arc_logits band gather -> float32
// ---------------------------------------------------------------------------
__global__ __launch_bounds__(256) void band_kernel(const float* __restrict__ Ap,
                                                   float* __restrict__ arc)
{
  int idx = blockIdx.x*256 + threadIdx.x;
  int c = idx % S_;
  int rr = (idx / S_) % S_;
  int b = idx / (S_*S_);
  int start = rr - MSTEP_; if (start < 0) start = 0;
  bool valid = (c >= start) && (c < rr);
  float v = 0.f;
  if (valid) v = Ap[(size_t)(b*S_ + rr)*MSTEP_ + (c - start)];
  arc[idx] = v;
}

// ---------------------------------------------------------------------------
extern "C" void kernel_launch(void* const* d_in, const int* in_sizes, int n_in,
                              void* d_out, int out_size, void* d_ws, size_t ws_size,
                              hipStream_t stream)
{
  const float* inp  = (const float*)d_in[0];
  const float* tag  = (const float*)d_in[1];
  const int*   mask = (const int*)d_in[2];
  const float* sent = (const float*)d_in[3];
  const float* Wihf = (const float*)d_in[4];
  const float* Whhf = (const float*)d_in[5];
  const float* bihf = (const float*)d_in[6];
  const float* bhhf = (const float*)d_in[7];
  const float* Wihb = (const float*)d_in[8];
  const float* Whhb = (const float*)d_in[9];
  const float* bihb = (const float*)d_in[10];
  const float* bhhb = (const float*)d_in[11];
  const float* Wg2e = (const float*)d_in[12];
  const float* bg2e = (const float*)d_in[13];
  const float* WihE = (const float*)d_in[14];
  const float* WhhE = (const float*)d_in[15];
  const float* bihE = (const float*)d_in[16];
  const float* bhhE = (const float*)d_in[17];
  const float* Wcls = (const float*)d_in[18];
  const float* bcls = (const float*)d_in[19];
  const float* bos  = (const float*)d_in[20];
  const float* Wht  = (const float*)d_in[21];
  const float* bht  = (const float*)d_in[22];
  const float* Wdt  = (const float*)d_in[23];
  const float* bdt  = (const float*)d_in[24];
  (void)in_sizes; (void)n_in; (void)out_size; (void)ws_size;

  char* ws = (char*)d_ws;
  unsigned short* preT2  = (unsigned short*)ws;                        // 39,321,600 B
  unsigned short* gs     = (unsigned short*)(ws + 39321600);           // 39,321,600 B
  unsigned short* Wrnn3  = (unsigned short*)(ws + 78643200);           //    692,224 B
  unsigned short* Wihcat = (unsigned short*)(ws + 79335424);           //  1,433,600 B
  unsigned short* Wg2e_b = (unsigned short*)(ws + 80769024);           //    409,600 B
  unsigned short* Wtag_b = (unsigned short*)(ws + 81178624);           //    409,600 B
  unsigned short* WhhE_b = (unsigned short*)(ws + 81588224);           //    131,072 B
  unsigned long long* maskb = (unsigned long long*)(ws + 81719296);    //      3,072 B (end ~81.72 MB)
  // preT2 is dead after rnn_mfma4; proj/Ap alias into it.
  float*          proj   = (float*)ws;                                 // 25,165,824 B (alias)
  float*          Ap     = (float*)(ws + 25165824);                    //  1,966,080 B (alias)

  float* outH   = (float*)d_out;                 // f32: reference output dtype
  float* outArc = outH + 2*HEAD_SZ_;

  hipLaunchKernelGGL(cvt4, dim3(350), dim3(256), 0, stream, Wihf, Wihcat,           400*896/4);
  hipLaunchKernelGGL(cvt4, dim3(350), dim3(256), 0, stream, Wihb, Wihcat + 400*896, 400*896/4);
  hipLaunchKernelGGL(cvt4, dim3(200), dim3(256), 0, stream, Wg2e, Wg2e_b,           256*800/4);
  hipLaunchKernelGGL(cvt4, dim3(100), dim3(256), 0, stream, Wht,  Wtag_b,           128*800/4);
  hipLaunchKernelGGL(cvt4, dim3(100), dim3(256), 0, stream, Wdt,  Wtag_b + 128*800, 128*800/4);
  hipLaunchKernelGGL(cvt4, dim3(64),  dim3(256), 0, stream, WhhE, WhhE_b,           256*256/4);
  hipLaunchKernelGGL(pack_wrnn3, dim3(1352), dim3(256), 0, stream, Whhf, Whhb, Wrnn3);
  hipLaunchKernelGGL(maskpack, dim3(S_), dim3(64), 0, stream, mask, maskb);
  hipLaunchKernelGGL(gemm_pre, dim3(9600), dim3(256), 0, stream,
                     inp, tag, sent, Wihcat, bihf, bhhf, bihb, bhhb, preT2);
  hipLaunchKernelGGL(rnn_mfma4, dim3(2), dim3(512), 0, stream, preT2, Wrnn3, maskb, gs);
  hipLaunchKernelGGL(gemm_proj, dim3(3072), dim3(256), 0, stream, gs, Wg2e_b, bg2e, proj);
  hipLaunchKernelGGL(gemm_tag,  dim3(3072), dim3(256), 0, stream, gs, Wtag_b, bht, bdt, outH);
  hipLaunchKernelGGL(estep2, dim3(256), dim3(256), 0, stream,
                     proj, WhhE_b, bihE, bhhE, WihE, Wcls, bcls, bos, Ap);
  hipLaunchKernelGGL(band_kernel, dim3(36864), dim3(256), 0, stream, Ap, outArc);
}

// Round 5
// 2283.886 us; speedup vs baseline: 5.6615x; 3.3690x over previous
//
#include <hip/hip_runtime.h>

#define B_ 64
#define T_ 383
#define S_ 384
#define ENC_ 768
#define TAGD_ 128
#define D_ 896
#define HG_ 400
#define HE_ 256
#define MSTEP_ 20
#define RTOT_ (B_*S_)                    // 24576
#define HEAD_SZ_ ((size_t)RTOT_*TAGD_)   // 3145728

typedef short short8 __attribute__((ext_vector_type(8)));
typedef float f32x4 __attribute__((ext_vector_type(4)));

__device__ __forceinline__ float bf2f(unsigned short u){
  union { unsigned int i; float f; } v; v.i = ((unsigned int)u) << 16; return v.f;
}
__device__ __forceinline__ unsigned short f2bf(float f){
  union { float f; unsigned int i; } v; v.f = f;
  unsigned int r = (v.i + 0x7fffu + ((v.i >> 16) & 1u)) >> 16;
  return (unsigned short)r;
}
__device__ __forceinline__ float tanh_fast(float x){
  float xc = fminf(fmaxf(x, -15.f), 15.f);
  float e = __expf(2.f*xc);
  return (e - 1.f) * __builtin_amdgcn_rcpf(e + 1.f);
}

// ---------------------------------------------------------------------------
// Runtime MFMA C/D-layout discovery (probe MFMAs) — used by the GEMM kernels.
// ---------------------------------------------------------------------------
__device__ __forceinline__ void probe_maps(int lane, int* mlab, int* nlab){
  unsigned short lb = f2bf((float)(lane & 15));
  short8 av, bv;
  #pragma unroll
  for (int j = 0; j < 8; j++){ av[j] = (short)lb; bv[j] = (short)0x3F80; } // bf16(1.0)
  f32x4 z = {0.f,0.f,0.f,0.f};
  f32x4 d1 = __builtin_amdgcn_mfma_f32_16x16x32_bf16(av, bv, z, 0, 0, 0);
  f32x4 d2 = __builtin_amdgcn_mfma_f32_16x16x32_bf16(bv, av, z, 0, 0, 0);
  #pragma unroll
  for (int i = 0; i < 4; i++){
    mlab[i] = (int)(d1[i]*0.03125f + 0.5f);
    nlab[i] = (int)(d2[i]*0.03125f + 0.5f);
  }
}

// Generic float -> bf16 (n multiple of 4)
__global__ __launch_bounds__(256) void cvt4(const float* __restrict__ src,
                                            unsigned short* __restrict__ dst, int n4)
{
  int i = blockIdx.x*256 + threadIdx.x;
  if (i >= n4) return;
  float4 v = ((const float4*)src)[i];
  ((ushort4*)dst)[i] = make_ushort4(f2bf(v.x), f2bf(v.y), f2bf(v.z), f2bf(v.w));
}

// ---------------------------------------------------------------------------
// Pack Whh into coalesced MFMA-B tile layout:
//   Wr[dir][tile:26][kt:13][r:16][kk:32], element = W[n=tile*16+r][k=kt*32+kk]
// ---------------------------------------------------------------------------
__global__ __launch_bounds__(256) void pack_wrnn3(const float* __restrict__ Wf,
                                                  const float* __restrict__ Wb,
                                                  unsigned short* __restrict__ Wr)
{
  int idx = blockIdx.x*256 + threadIdx.x;     // 2*26*13*16*32 = 346112 total
  if (idx >= 2*26*13*16*32) return;
  int dir = idx / (26*13*16*32);
  int rem = idx % (26*13*16*32);
  int tile = rem / (13*16*32); rem %= (13*16*32);
  int kt = rem / (16*32);      rem %= (16*32);
  int r  = rem / 32;
  int kk = rem % 32;
  int n = tile*16 + r, k = kt*32 + kk;
  unsigned short v = 0;
  if (n < HG_ && k < HG_) v = f2bf((dir ? Wb : Wf)[(size_t)n*HG_ + k]);
  Wr[idx] = v;
}

// ---------------------------------------------------------------------------
// Pack mask into per-t 64-bit bitmasks (bit b = mask[b][t-1]; t=0 -> all 1s).
// ---------------------------------------------------------------------------
__global__ __launch_bounds__(64) void maskpack(const int* __restrict__ mask,
                                               unsigned long long* __restrict__ mb)
{
  int t = blockIdx.x; int b = threadIdx.x;
  int m = (t > 0) ? mask[b*T_ + (t-1)] : 1;
  unsigned long long v = __ballot(m != 0);
  if (b == 0) mb[t] = v;
}

// ---------------------------------------------------------------------------
// preT2: fragment-order pre layout, so the RNN reads one coalesced ushort4
// per lane per (ntile, batch-group):
//   preT2[dir][t][nt:25][mt:4][lane:64][ri:4],
//   value = pre[b = mt*16 + (lane>>4)*4 + ri][n = nt*16 + (lane&15)]
// ---------------------------------------------------------------------------
__global__ __launch_bounds__(256) void gemm_pre(
    const float* __restrict__ inp, const float* __restrict__ tag,
    const float* __restrict__ sent, const unsigned short* __restrict__ W,
    const float* __restrict__ bihf, const float* __restrict__ bhhf,
    const float* __restrict__ bihb, const float* __restrict__ bhhb,
    unsigned short* __restrict__ preT2)
{
  int wid = blockIdx.x*4 + (threadIdx.x >> 6);
  int lane = threadIdx.x & 63;
  int q = lane >> 4, l16 = lane & 15;
  int mt = wid / 25, ct = wid % 25;
  int r = mt*16 + l16;
  int s = r % S_, b = r / S_;
  int mlab[4], nlab[4];
  probe_maps(lane, mlab, nlab);
  int n0 = ct*32 + l16, n1 = n0 + 16;
  const unsigned short* w0 = W + (size_t)n0*D_;
  const unsigned short* w1 = W + (size_t)n1*D_;
  f32x4 acc0 = {0.f,0.f,0.f,0.f}, acc1 = {0.f,0.f,0.f,0.f};
  for (int k0 = 0; k0 < D_; k0 += 32){
    int k = k0 + q*8;   // 8-float group never straddles the 768 boundary
    const float* asrc = (s == 0) ? (sent + k)
        : ((k < ENC_) ? inp + (size_t)(b*T_ + (s-1))*ENC_ + k
                      : tag + (size_t)(b*T_ + (s-1))*TAGD_ + (k - ENC_));
    float4 v0 = *(const float4*)asrc;
    float4 v1 = *(const float4*)(asrc + 4);
    short8 a;
    a[0]=(short)f2bf(v0.x); a[1]=(short)f2bf(v0.y); a[2]=(short)f2bf(v0.z); a[3]=(short)f2bf(v0.w);
    a[4]=(short)f2bf(v1.x); a[5]=(short)f2bf(v1.y); a[6]=(short)f2bf(v1.z); a[7]=(short)f2bf(v1.w);
    acc0 = __builtin_amdgcn_mfma_f32_16x16x32_bf16(a, *(const short8*)(w0 + k), acc0, 0,0,0);
    acc1 = __builtin_amdgcn_mfma_f32_16x16x32_bf16(a, *(const short8*)(w1 + k), acc1, 0,0,0);
  }
  #pragma unroll
  for (int i = 0; i < 4; i++){
    int row = mt*16 + mlab[i];
    int c0 = ct*32 + nlab[i], c1 = c0 + 16;
    int bb = row / S_, ss = row % S_;
    int mtb = bb >> 4, qb = (bb >> 2) & 3, rib = bb & 3;
    float v0 = acc0[i] + ((c0 < HG_) ? (bihf[c0] + bhhf[c0]) : (bihb[c0-HG_] + bhhb[c0-HG_]));
    float v1 = acc1[i] + ((c1 < HG_) ? (bihf[c1] + bhhf[c1]) : (bihb[c1-HG_] + bhhb[c1-HG_]));
    {
      int d = (c0 >= HG_) ? 1 : 0; int nn = c0 - d*HG_;
      int nt = nn >> 4, lc = nn & 15;
      preT2[((((size_t)(d*S_ + ss)*25 + nt)*4 + mtb)*64 + (qb*16 + lc))*4 + rib] = f2bf(v0);
    }
    {
      int d = (c1 >= HG_) ? 1 : 0; int nn = c1 - d*HG_;
      int nt = nn >> 4, lc = nn & 15;
      preT2[((((size_t)(d*S_ + ss)*25 + nt)*4 + mtb)*64 + (qb*16 + lc))*4 + rib] = f2bf(v1);
    }
  }
}

// ---------------------------------------------------------------------------
// Batched masked RNN via MFMA, BATCH-SPLIT: 8 blocks = 2 dirs x 4 groups of
// 16 batches. Per block: 8 waves (512 thr), n-split over 25 live tiles
// (wave 0: 4 tiles, waves 1-7: 3 tiles; 400 = 25*16 exactly, no guards).
// m-tile = 1 (the block's 16 batches). Whh kt 0..5 held in registers
// (72-96 VGPR, estep2-proven pattern), kt 6..12 streamed from L2
// (halves per-step B traffic). H hi/lo bf16 planes in LDS (f32-accurate),
// in-place update, 2 barriers/step, coalesced masked LDS->global gs copy.
// ---------------------------------------------------------------------------
#define HSTR5_ 424   // shorts per H row (416 + 8 pad; multiple of 8 for b128)
template<int NTC>
__device__ void rnn_body5(int nt0, int dir, int bg, int lane, int tid,
    const unsigned short* __restrict__ pD,     // this dir: [t][25][4][64][4]
    const unsigned short* __restrict__ Wd,     // this dir: [26][13][16][32]
    const unsigned long long* __restrict__ mbits,
    unsigned short* __restrict__ gs,
    unsigned short (*Hh)[HSTR5_], unsigned short (*Hl)[HSTR5_])
{
  int q = lane >> 4, l16 = lane & 15;
  const unsigned short* wrow[NTC];
  #pragma unroll
  for (int j = 0; j < NTC; j++)
    wrow[j] = Wd + (size_t)(nt0 + j)*13*512 + l16*32 + q*8;

  // held B fragments: kt 0..5 (one-time load, L2/HBM)
  short8 bh[NTC][6];
  #pragma unroll
  for (int j = 0; j < NTC; j++)
    #pragma unroll
    for (int kt = 0; kt < 6; kt++)
      bh[j][kt] = *(const short8*)(wrow[j] + kt*512);

  for (int stp = 0; stp < S_; stp++){
    int t = dir ? (S_ - 1 - stp) : stp;
    unsigned long long mb = mbits[t];
    bool allm = (mb == 0xFFFFFFFFFFFFFFFFull);
    const unsigned short* pT = pD + (size_t)t*25600;   // 25*4*64*4

    // pre fragments for this step's epilogue (HBM latency hides under MFMA)
    ushort4 pu[NTC];
    #pragma unroll
    for (int j = 0; j < NTC; j++)
      pu[j] = *(const ushort4*)(pT + (((size_t)(nt0 + j)*4 + bg)*64 + lane)*4);

    f32x4 acc[NTC];
    #pragma unroll
    for (int j = 0; j < NTC; j++) acc[j] = (f32x4){0.f,0.f,0.f,0.f};

    // streamed kts first (loads issue early), held kts fill the load latency
    #pragma unroll
    for (int kt = 6; kt < 13; kt++){
      short8 bv[NTC];
      #pragma unroll
      for (int j = 0; j < NTC; j++) bv[j] = *(const short8*)(wrow[j] + kt*512);
      short8 ah = *(const short8*)&Hh[l16][kt*32 + q*8];
      short8 al = *(const short8*)&Hl[l16][kt*32 + q*8];
      #pragma unroll
      for (int j = 0; j < NTC; j++){
        acc[j] = __builtin_amdgcn_mfma_f32_16x16x32_bf16(ah, bv[j], acc[j], 0,0,0);
        acc[j] = __builtin_amdgcn_mfma_f32_16x16x32_bf16(al, bv[j], acc[j], 0,0,0);
      }
    }
    #pragma unroll
    for (int kt = 0; kt < 6; kt++){
      short8 ah = *(const short8*)&Hh[l16][kt*32 + q*8];
      short8 al = *(const short8*)&Hl[l16][kt*32 + q*8];
      #pragma unroll
      for (int j = 0; j < NTC; j++){
        acc[j] = __builtin_amdgcn_mfma_f32_16x16x32_bf16(ah, bh[j][kt], acc[j], 0,0,0);
        acc[j] = __builtin_amdgcn_mfma_f32_16x16x32_bf16(al, bh[j][kt], acc[j], 0,0,0);
      }
    }

    __syncthreads();   // all waves done reading H this step

    #pragma unroll
    for (int j = 0; j < NTC; j++){
      int n = (nt0 + j)*16 + l16;
      unsigned short pv[4] = {pu[j].x, pu[j].y, pu[j].z, pu[j].w};
      #pragma unroll
      for (int ri = 0; ri < 4; ri++){
        int b = q*4 + ri;                       // local batch row 0..15
        float hn = tanh_fast(acc[j][ri] + bf2f(pv[ri]));
        float hnew;
        if (allm) hnew = hn;
        else {
          bool mv = (mb >> (bg*16 + b)) & 1ull;
          float hold = bf2f(Hh[b][n]) + bf2f(Hl[b][n]);   // pre-overwrite
          hnew = mv ? hn : hold;
        }
        unsigned short hi = f2bf(hnew);
        Hh[b][n] = hi;
        Hl[b][n] = f2bf(hnew - bf2f(hi));
      }
    }
    __syncthreads();   // H writes visible to all

    // coalesced masked gs copy: 16 rows x 400 shorts = 800 uint4 jobs
    for (int c = tid; c < 800; c += 512){
      int b = c / 50, off = c - b*50;
      uint4 dv = *(const uint4*)&Hh[b][off*8];
      bool mv = (mb >> (bg*16 + b)) & 1ull;
      uint4 z = make_uint4(0,0,0,0);
      *(uint4*)(gs + (size_t)((bg*16 + b)*S_ + t)*800 + dir*HG_ + off*8) = mv ? dv : z;
    }
    // no third barrier: copy only reads Hh; next write to Hh is after the
    // next step's post-MFMA barrier, which orders these ds_reads.
  }
}

__global__ __launch_bounds__(512, 1) void rnn_mfma5(
    const unsigned short* __restrict__ preT2, const unsigned short* __restrict__ Wr,
    const unsigned long long* __restrict__ mbits, unsigned short* __restrict__ gs)
{
  __shared__ __align__(16) unsigned short Hh[16][HSTR5_];
  __shared__ __align__(16) unsigned short Hl[16][HSTR5_];
  int tid = threadIdx.x;
  int wave = tid >> 6, lane = tid & 63;
  int dir = blockIdx.x >> 2, bg = blockIdx.x & 3;
  for (int i = tid; i < 16*HSTR5_/2; i += 512){
    ((unsigned int*)Hh)[i] = 0u;
    ((unsigned int*)Hl)[i] = 0u;
  }
  __syncthreads();
  const unsigned short* Wd = Wr + (size_t)dir*26*13*512;
  const unsigned short* pD = preT2 + (size_t)dir*S_*25600;
  if (wave == 0) rnn_body5<4>(0,                dir, bg, lane, tid, pD, Wd, mbits, gs, Hh, Hl);
  else           rnn_body5<3>(4 + (wave-1)*3,   dir, bg, lane, tid, pD, Wd, mbits, gs, Hh, Hl);
}

// ---------------------------------------------------------------------------
// proj[r][n] = gs[r] . Wg2e[n] + bg2e[n]   (K=800, N=256), fp32 out
// ---------------------------------------------------------------------------
__global__ __launch_bounds__(256) void gemm_proj(
    const unsigned short* __restrict__ gs, const unsigned short* __restrict__ Wg2e,
    const float* __restrict__ bg2e, float* __restrict__ proj)
{
  int wid = blockIdx.x*4 + (threadIdx.x >> 6);
  int lane = threadIdx.x & 63;
  int q = lane >> 4, l16 = lane & 15;
  int mt = wid >> 3, ct = wid & 7;
  int mlab[4], nlab[4];
  probe_maps(lane, mlab, nlab);
  const unsigned short* arow = gs + (size_t)(mt*16 + l16)*800;
  int n0 = ct*32 + l16, n1 = n0 + 16;
  const unsigned short* w0 = Wg2e + (size_t)n0*800;
  const unsigned short* w1 = Wg2e + (size_t)n1*800;
  f32x4 acc0 = {0.f,0.f,0.f,0.f}, acc1 = {0.f,0.f,0.f,0.f};
  for (int k0 = 0; k0 < 800; k0 += 32){
    int k = k0 + q*8;
    short8 a = *(const short8*)(arow + k);
    acc0 = __builtin_amdgcn_mfma_f32_16x16x32_bf16(a, *(const short8*)(w0 + k), acc0, 0,0,0);
    acc1 = __builtin_amdgcn_mfma_f32_16x16x32_bf16(a, *(const short8*)(w1 + k), acc1, 0,0,0);
  }
  #pragma unroll
  for (int i = 0; i < 4; i++){
    int row = mt*16 + mlab[i];
    int c0 = ct*32 + nlab[i], c1 = c0 + 16;
    proj[(size_t)row*HE_ + c0] = acc0[i] + bg2e[c0];
    proj[(size_t)row*HE_ + c1] = acc1[i] + bg2e[c1];
  }
}

// ---------------------------------------------------------------------------
// head_tag / dep_tag = elu(gs @ Wtag^T + b), N=256 (c<128 head, else dep).
// ---------------------------------------------------------------------------
__global__ __launch_bounds__(256) void gemm_tag(
    const unsigned short* __restrict__ gs, const unsigned short* __restrict__ Wtag,
    const float* __restrict__ bht, const float* __restrict__ bdt,
    float* __restrict__ outH)
{
  int wid = blockIdx.x*4 + (threadIdx.x >> 6);
  int lane = threadIdx.x & 63;
  int q = lane >> 4, l16 = lane & 15;
  int mt = wid >> 3, ct = wid & 7;
  int mlab[4], nlab[4];
  probe_maps(lane, mlab, nlab);
  const unsigned short* arow = gs + (size_t)(mt*16 + l16)*800;
  int n0 = ct*32 + l16, n1 = n0 + 16;
  const unsigned short* w0 = Wtag + (size_t)n0*800;
  const unsigned short* w1 = Wtag + (size_t)n1*800;
  f32x4 acc0 = {0.f,0.f,0.f,0.f}, acc1 = {0.f,0.f,0.f,0.f};
  for (int k0 = 0; k0 < 800; k0 += 32){
    int k = k0 + q*8;
    short8 a = *(const short8*)(arow + k);
    acc0 = __builtin_amdgcn_mfma_f32_16x16x32_bf16(a, *(const short8*)(w0 + k), acc0, 0,0,0);
    acc1 = __builtin_amdgcn_mfma_f32_16x16x32_bf16(a, *(const short8*)(w1 + k), acc1, 0,0,0);
  }
  #pragma unroll
  for (int i = 0; i < 4; i++){
    int row = mt*16 + mlab[i];
    int c0 = ct*32 + nlab[i], c1 = c0 + 16;
    float v0 = acc0[i] + ((c0 < TAGD_) ? bht[c0] : bdt[c0-TAGD_]);
    float v1 = acc1[i] + ((c1 < TAGD_) ? bht[c1] : bdt[c1-TAGD_]);
    v0 = (v0 > 0.f) ? v0 : expm1f(v0);
    v1 = (v1 > 0.f) ? v1 : expm1f(v1);
    if (c0 < TAGD_) outH[(size_t)row*TAGD_ + c0] = v0;
    else            outH[HEAD_SZ_ + (size_t)row*TAGD_ + (c0-TAGD_)] = v0;
    if (c1 < TAGD_) outH[(size_t)row*TAGD_ + c1] = v1;
    else            outH[HEAD_SZ_ + (size_t)row*TAGD_ + (c1-TAGD_)] = v1;
  }
}

// ---------------------------------------------------------------------------
// estep scan, register-resident WhhE.
// ---------------------------------------------------------------------------
#define EROWS_ 96
#define ESTR_ 264
__global__ __launch_bounds__(256, 1) void estep2(
    const float* __restrict__ proj, const unsigned short* __restrict__ WhhE,
    const float* __restrict__ bihE, const float* __restrict__ bhhE,
    const float* __restrict__ WihE, const float* __restrict__ Wcls,
    const float* __restrict__ bclsp, const float* __restrict__ bosp,
    float* __restrict__ Ap)
{
  __shared__ __align__(16) unsigned short H[2][EROWS_][ESTR_];
  __shared__ float lacc[4][EROWS_];
  __shared__ float xls[EROWS_];
  int tid = threadIdx.x;
  int wave = tid >> 6, lane = tid & 63, q = lane >> 4, l16 = lane & 15;
  size_t rowbase = (size_t)blockIdx.x * EROWS_;

  short8 bw[4][8];
  float bias_n[4], wcl_n[4], wih_n[4];
  #pragma unroll
  for (int nt = 0; nt < 4; nt++){
    int n = wave*64 + nt*16 + l16;
    #pragma unroll
    for (int kt = 0; kt < 8; kt++)
      bw[nt][kt] = *(const short8*)(WhhE + (size_t)n*HE_ + kt*32 + q*8);
    bias_n[nt] = bihE[n] + bhhE[n];
    wcl_n[nt]  = Wcls[n];
    wih_n[nt]  = WihE[n];
  }
  for (int i = tid; i < EROWS_*HE_; i += 256){
    int r = i >> 8, n = i & 255;
    H[0][r][n] = f2bf(proj[(rowbase + r)*HE_ + n]);
  }
  if (tid < EROWS_) xls[tid] = bosp[0];
  float bc = bclsp[0];
  __syncthreads();

  for (int stp = 0; stp < MSTEP_; stp++){
    int cur = stp & 1, nxt = cur ^ 1;
    float lp[6][4];
    #pragma unroll
    for (int mt = 0; mt < 6; mt++){
      short8 af[8];
      #pragma unroll
      for (int kt = 0; kt < 8; kt++)
        af[kt] = *(const short8*)&H[cur][mt*16 + l16][kt*32 + q*8];
      float xr[4];
      #pragma unroll
      for (int ri = 0; ri < 4; ri++) xr[ri] = xls[mt*16 + q*4 + ri];
      f32x4 acc[4];
      #pragma unroll
      for (int nt = 0; nt < 4; nt++) acc[nt] = (f32x4){0.f,0.f,0.f,0.f};
      #pragma unroll
      for (int kt = 0; kt < 8; kt++){
        #pragma unroll
        for (int nt = 0; nt < 4; nt++)
          acc[nt] = __builtin_amdgcn_mfma_f32_16x16x32_bf16(af[kt], bw[nt][kt], acc[nt], 0,0,0);
      }
      #pragma unroll
      for (int ri = 0; ri < 4; ri++) lp[mt][ri] = 0.f;
      #pragma unroll
      for (int nt = 0; nt < 4; nt++){
        int n = wave*64 + nt*16 + l16;
        #pragma unroll
        for (int ri = 0; ri < 4; ri++){
          float v = acc[nt][ri] + bias_n[nt] + xr[ri]*wih_n[nt];
          float h = tanh_fast(v);
          lp[mt][ri] += h * wcl_n[nt];
          H[nxt][mt*16 + q*4 + ri][n] = f2bf(h);
        }
      }
    }
    #pragma unroll
    for (int mt = 0; mt < 6; mt++){
      #pragma unroll
      for (int ri = 0; ri < 4; ri++){
        float v = lp[mt][ri];
        v += __shfl_xor(v, 1, 16);
        v += __shfl_xor(v, 2, 16);
        v += __shfl_xor(v, 4, 16);
        v += __shfl_xor(v, 8, 16);
        lp[mt][ri] = v;
      }
    }
    if (l16 == 0){
      #pragma unroll
      for (int mt = 0; mt < 6; mt++)
        #pragma unroll
        for (int ri = 0; ri < 4; ri++)
          lacc[wave][mt*16 + q*4 + ri] = lp[mt][ri];
    }
    __syncthreads();
    if (tid < EROWS_){
      float lg = lacc[0][tid] + lacc[1][tid] + lacc[2][tid] + lacc[3][tid] + bc;
      Ap[(rowbase + tid)*MSTEP_ + stp] = lg;
      xls[tid] = lg;
    }
    __syncthreads();
  }
}

// ---------------------------------------------------------------------------
// arc_logits band gather -> float32
// ---------------------------------------------------------------------------
__global__ __launch_bounds__(256) void band_kernel(const float* __restrict__ Ap,
                                                   float* __restrict__ arc)
{
  int idx = blockIdx.x*256 + threadIdx.x;
  int c = idx % S_;
  int rr = (idx / S_) % S_;
  int b = idx / (S_*S_);
  int start = rr - MSTEP_; if (start < 0) start = 0;
  bool valid = (c >= start) && (c < rr);
  float v = 0.f;
  if (valid) v = Ap[(size_t)(b*S_ + rr)*MSTEP_ + (c - start)];
  arc[idx] = v;
}

// ---------------------------------------------------------------------------
extern "C" void kernel_launch(void* const* d_in, const int* in_sizes, int n_in,
                              void* d_out, int out_size, void* d_ws, size_t ws_size,
                              hipStream_t stream)
{
  const float* inp  = (const float*)d_in[0];
  const float* tag  = (const float*)d_in[1];
  const int*   mask = (const int*)d_in[2];
  const float* sent = (const float*)d_in[3];
  const float* Wihf = (const float*)d_in[4];
  const float* Whhf = (const float*)d_in[5];
  const float* bihf = (const float*)d_in[6];
  const float* bhhf = (const float*)d_in[7];
  const float* Wihb = (const float*)d_in[8];
  const float* Whhb = (const float*)d_in[9];
  const float* bihb = (const float*)d_in[10];
  const float* bhhb = (const float*)d_in[11];
  const float* Wg2e = (const float*)d_in[12];
  const float* bg2e = (const float*)d_in[13];
  const float* WihE = (const float*)d_in[14];
  const float* WhhE = (const float*)d_in[15];
  const float* bihE = (const float*)d_in[16];
  const float* bhhE = (const float*)d_in[17];
  const float* Wcls = (const float*)d_in[18];
  const float* bcls = (const float*)d_in[19];
  const float* bos  = (const float*)d_in[20];
  const float* Wht  = (const float*)d_in[21];
  const float* bht  = (const float*)d_in[22];
  const float* Wdt  = (const float*)d_in[23];
  const float* bdt  = (const float*)d_in[24];
  (void)in_sizes; (void)n_in; (void)out_size; (void)ws_size;

  char* ws = (char*)d_ws;
  unsigned short* preT2  = (unsigned short*)ws;                        // 39,321,600 B
  unsigned short* gs     = (unsigned short*)(ws + 39321600);           // 39,321,600 B
  unsigned short* Wrnn3  = (unsigned short*)(ws + 78643200);           //    692,224 B
  unsigned short* Wihcat = (unsigned short*)(ws + 79335424);           //  1,433,600 B
  unsigned short* Wg2e_b = (unsigned short*)(ws + 80769024);           //    409,600 B
  unsigned short* Wtag_b = (unsigned short*)(ws + 81178624);           //    409,600 B
  unsigned short* WhhE_b = (unsigned short*)(ws + 81588224);           //    131,072 B
  unsigned long long* maskb = (unsigned long long*)(ws + 81719296);    //      3,072 B (end ~81.72 MB)
  // preT2 is dead after rnn_mfma5; proj/Ap alias into it.
  float*          proj   = (float*)ws;                                 // 25,165,824 B (alias)
  float*          Ap     = (float*)(ws + 25165824);                    //  1,966,080 B (alias)

  float* outH   = (float*)d_out;                 // f32: reference output dtype
  float* outArc = outH + 2*HEAD_SZ_;

  hipLaunchKernelGGL(cvt4, dim3(350), dim3(256), 0, stream, Wihf, Wihcat,           400*896/4);
  hipLaunchKernelGGL(cvt4, dim3(350), dim3(256), 0, stream, Wihb, Wihcat + 400*896, 400*896/4);
  hipLaunchKernelGGL(cvt4, dim3(200), dim3(256), 0, stream, Wg2e, Wg2e_b,           256*800/4);
  hipLaunchKernelGGL(cvt4, dim3(100), dim3(256), 0, stream, Wht,  Wtag_b,           128*800/4);
  hipLaunchKernelGGL(cvt4, dim3(100), dim3(256), 0, stream, Wdt,  Wtag_b + 128*800, 128*800/4);
  hipLaunchKernelGGL(cvt4, dim3(64),  dim3(256), 0, stream, WhhE, WhhE_b,           256*256/4);
  hipLaunchKernelGGL(pack_wrnn3, dim3(1352), dim3(256), 0, stream, Whhf, Whhb, Wrnn3);
  hipLaunchKernelGGL(maskpack, dim3(S_), dim3(64), 0, stream, mask, maskb);
  hipLaunchKernelGGL(gemm_pre, dim3(9600), dim3(256), 0, stream,
                     inp, tag, sent, Wihcat, bihf, bhhf, bihb, bhhb, preT2);
  hipLaunchKernelGGL(rnn_mfma5, dim3(8), dim3(512), 0, stream, preT2, Wrnn3, maskb, gs);
  hipLaunchKernelGGL(gemm_proj, dim3(3072), dim3(256), 0, stream, gs, Wg2e_b, bg2e, proj);
  hipLaunchKernelGGL(gemm_tag,  dim3(3072), dim3(256), 0, stream, gs, Wtag_b, bht, bdt, outH);
  hipLaunchKernelGGL(estep2, dim3(256), dim3(256), 0, stream,
                     proj, WhhE_b, bihE, bhhE, WihE, Wcls, bcls, bos, Ap);
  hipLaunchKernelGGL(band_kernel, dim3(36864), dim3(256), 0, stream, Ap, outArc);
}